// Round 9
// baseline (238.719 us; speedup 1.0000x reference)
//
#include <hip/hip_runtime.h>

#define PI2 6.28318530717958647692f

// D = 10000 = 100 x 100; F = 5001; signals: 128 pos + 10 atom + 1 closure = 139
#define NSIG 139
#define FS   5120      // spectrum row stride (float2)

// ---------------- twiddle tables ----------------
__global__ void k_tables(float* __restrict__ t100c, float* __restrict__ t100s,
                         float* __restrict__ twc,   float* __restrict__ tws) {
  int idx = blockIdx.x * 256 + threadIdx.x;
  if (idx >= 10000) return;
  int j = idx / 100, m = idx % 100;
  int r1 = (j * m) % 100;
  float a1 = PI2 * (float)r1 * 0.01f;
  float s1, c1; sincosf(a1, &s1, &c1);
  t100c[idx] = c1; t100s[idx] = s1;
  int r2 = (j * m) % 10000;
  float a2 = PI2 * (float)r2 * 0.0001f;
  float s2, c2; sincosf(a2, &s2, &c2);
  twc[idx] = c2; tws[idx] = s2;
}

// ---------------- forward stage 1 (Hermitian-paired, LDS-staged) ----------------
// Block = (sig, split). Signal x (10000 floats, 40 KB) staged in LDS once,
// then each thread computes one (k1, 4x n2) tile: ar=SUM x*cos, as=SUM x*sin,
// writing post-twiddle rows k1 AND (100-k1)%100. tiles/sig = 51*25 = 1275 (5 splits).
__global__ void k_f1(const float* __restrict__ atom, const float* __restrict__ pos,
                     const float* __restrict__ clo,
                     const float* __restrict__ t100c, const float* __restrict__ t100s,
                     const float* __restrict__ twc, const float* __restrict__ tws,
                     float2* __restrict__ Bbuf) {
  __shared__ float xs[10000];
  unsigned sig = blockIdx.x;
  const float* xb = (sig < 128u) ? (pos + sig * 10000u)
                   : ((sig < 138u) ? (atom + (sig - 128u) * 10000u) : clo);
  for (int i = threadIdx.x; i < 2500; i += 256)
    *(float4*)(xs + 4 * i) = *(const float4*)(xb + 4 * i);
  __syncthreads();
  unsigned tt = blockIdx.y * 256u + threadIdx.x;
  if (tt >= 1275u) return;
  unsigned k1 = tt / 25u, n2 = (tt % 25u) * 4u;
  float ar[4] = {}, as[4] = {};
#pragma unroll 4
  for (int n1 = 0; n1 < 100; ++n1) {
    const float4 xv = *(const float4*)(xs + n1 * 100 + n2);   // LDS, contiguous b128
    const float c = t100c[n1 * 100 + k1];                      // broadcast (L1)
    const float s = t100s[n1 * 100 + k1];
    ar[0] += xv.x * c; as[0] += xv.x * s;
    ar[1] += xv.y * c; as[1] += xv.y * s;
    ar[2] += xv.z * c; as[2] += xv.z * s;
    ar[3] += xv.w * c; as[3] += xv.w * s;
  }
  unsigned rb = (100u - k1) % 100u;
  float2* rowA = Bbuf + sig * 10000u + k1 * 100u + n2;
  float2* rowB = Bbuf + sig * 10000u + rb * 100u + n2;
#pragma unroll
  for (int j = 0; j < 4; ++j) {
    // row k1:  (ar - i*as) * (cwA - i*swA)
    float cwA = twc[(n2 + j) * 100 + k1];
    float swA = tws[(n2 + j) * 100 + k1];
    rowA[j] = make_float2(ar[j] * cwA - as[j] * swA,
                          -(as[j] * cwA + ar[j] * swA));
    // row 100-k1: (ar + i*as) * (cwB - i*swB)
    float cwB = twc[(n2 + j) * 100 + rb];
    float swB = tws[(n2 + j) * 100 + rb];
    rowB[j] = make_float2(ar[j] * cwB + as[j] * swB,
                          as[j] * cwB - ar[j] * swB);
  }
}

// ---------------- forward stage 2 (LDS-staged): X[k1+100k2] = sum_n2 B[k1][n2] w^{n2 k2} ----------------
// Block = (sig, half, split). 50 B rows (40 KB) staged; thread tile 2 k1 x 2 k2,
// k2 fastest across lanes (LDS row broadcast, twiddle coalesced). 650 tiles / half (3 splits).
__global__ void k_f2(const float2* __restrict__ Bbuf,
                     const float* __restrict__ t100c, const float* __restrict__ t100s,
                     float2* __restrict__ spec) {
  __shared__ float bs[10000];   // 50 rows x 100 complex
  unsigned sig = blockIdx.x, half = blockIdx.y;
  const float* bp = (const float*)(Bbuf + sig * 10000u + half * 5000u);
  for (int i = threadIdx.x; i < 2500; i += 256)
    *(float4*)(bs + 4 * i) = *(const float4*)(bp + 4 * i);
  __syncthreads();
  unsigned tt = blockIdx.z * 256u + threadIdx.x;
  if (tt >= 650u) return;
  unsigned k1l = (tt / 26u) * 2u;   // local row, 25 groups
  unsigned k2 = (tt % 26u) * 2u;    // 26 groups, fastest
  const float* brow0 = bs + k1l * 200u;
  const float* brow1 = brow0 + 200;
  float re[2][2] = {}, im[2][2] = {};
#pragma unroll 4
  for (int n2 = 0; n2 < 100; n2 += 2) {
    const float4 b0 = *(const float4*)(brow0 + 2 * n2);  // 2 complex of row k1l (LDS)
    const float4 b1 = *(const float4*)(brow1 + 2 * n2);  // row k1l+1
    const float2 c0 = *(const float2*)(t100c + n2 * 100 + k2);
    const float2 s0 = *(const float2*)(t100s + n2 * 100 + k2);
    const float2 c1 = *(const float2*)(t100c + (n2 + 1) * 100 + k2);
    const float2 s1 = *(const float2*)(t100s + (n2 + 1) * 100 + k2);
    const float cc0[2] = {c0.x, c0.y}, ss0[2] = {s0.x, s0.y};
    const float cc1[2] = {c1.x, c1.y}, ss1[2] = {s1.x, s1.y};
#pragma unroll
    for (int j = 0; j < 2; ++j) {
      re[0][j] += b0.x * cc0[j] + b0.y * ss0[j];
      im[0][j] += b0.y * cc0[j] - b0.x * ss0[j];
      re[1][j] += b1.x * cc0[j] + b1.y * ss0[j];
      im[1][j] += b1.y * cc0[j] - b1.x * ss0[j];
      re[0][j] += b0.z * cc1[j] + b0.w * ss1[j];
      im[0][j] += b0.w * cc1[j] - b0.z * ss1[j];
      re[1][j] += b1.z * cc1[j] + b1.w * ss1[j];
      im[1][j] += b1.w * cc1[j] - b1.z * ss1[j];
    }
  }
  unsigned k1 = half * 50u + k1l;
#pragma unroll
  for (int i = 0; i < 2; ++i)
#pragma unroll
    for (int j = 0; j < 2; ++j) {
      unsigned k = (k1 + i) + 100u * (k2 + j);
      if (k <= 5000u)
        spec[sig * FS + k] = make_float2(re[i][j], im[i][j]);
    }
}

// ---------------- mix (LDS-staged Fp): freq[b,k] = sum_s tm*Fa[aidx]*Fp[s] + rings ----------------
// b-tile 4, grid (20 k-chunks, 16 b-groups). Fp staged in s-chunks of 16
// (16 x 256 float2 = 32 KB): staging is 16 independent coalesced loads/thread,
// compute reads LDS only -> latency hidden (round-8 k_mix was 8% occ, 20% VALU).
__global__ void k_mix(const float2* __restrict__ spec,
                      const float* __restrict__ tmask, const float* __restrict__ rmask,
                      const int* __restrict__ aidx, const int* __restrict__ rpos,
                      float2* __restrict__ G) {
  __shared__ float2 FaS[10][256];
  __shared__ float2 FcS[256];
  __shared__ float2 FpS[16][256];
  __shared__ float tmS[4][128];
  __shared__ int   aiS[4][128];
  __shared__ float rmS[4][8];
  __shared__ int   rpS[4][8][2];
  int tid = threadIdx.x;
  int k0 = blockIdx.x * 256;
  int k = k0 + tid;
  int kc = k > 5000 ? 5000 : k;
  int b0 = blockIdx.y * 4;
#pragma unroll
  for (int a = 0; a < 10; ++a) FaS[a][tid] = spec[(128 + a) * FS + kc];
  FcS[tid] = spec[138 * FS + kc];
  for (int i = tid; i < 4 * 128; i += 256) {
    int bb = i >> 7, ss = i & 127;
    tmS[bb][ss] = tmask[(b0 + bb) * 128 + ss];
    aiS[bb][ss] = aidx[(b0 + bb) * 128 + ss];
  }
  if (tid < 32) {
    int bb = tid >> 3, rr = tid & 7;
    rmS[bb][rr] = rmask[(b0 + bb) * 8 + rr];
    rpS[bb][rr][0] = rpos[((b0 + bb) * 8 + rr) * 2 + 0];
    rpS[bb][rr][1] = rpos[((b0 + bb) * 8 + rr) * 2 + 1];
  }
  float fr[4] = {}, fi[4] = {};
  for (int sc = 0; sc < 128; sc += 16) {
    __syncthreads();
    // stage Fp rows sc..sc+15 for this k-chunk (coalesced float2 per lane)
#pragma unroll
    for (int srow = 0; srow < 16; ++srow)
      FpS[srow][tid] = spec[(sc + srow) * FS + kc];
    __syncthreads();
#pragma unroll 4
    for (int sl = 0; sl < 16; ++sl) {
      int s = sc + sl;
      float2 fp = FpS[sl][tid];
#pragma unroll
      for (int b = 0; b < 4; ++b) {
        int a = aiS[b][s];
        float tm = tmS[b][s];
        float2 fa = FaS[a][tid];
        float tr = fa.x * fp.x - fa.y * fp.y;
        float ti = fa.x * fp.y + fa.y * fp.x;
        fr[b] += tm * tr;
        fi[b] += tm * ti;
      }
    }
  }
  float2 fc = FcS[tid];
#pragma unroll
  for (int r = 0; r < 8; ++r) {
#pragma unroll
    for (int b = 0; b < 4; ++b) {
      int p0 = rpS[b][r][0], p1 = rpS[b][r][1];
      float rm = rmS[b][r];
      float2 f0 = spec[p0 * FS + kc];
      float2 f1 = spec[p1 * FS + kc];
      float tr = f0.x * f1.x - f0.y * f1.y;
      float ti = f0.x * f1.y + f0.y * f1.x;
      float ur = tr * fc.x - ti * fc.y;
      float ui = tr * fc.y + ti * fc.x;
      fr[b] += rm * ur;
      fi[b] += rm * ui;
    }
  }
  if (k <= 5000) {
#pragma unroll
    for (int b = 0; b < 4; ++b) {
      float fib = (k == 0 || k == 5000) ? 0.0f : fi[b];  // exact Hermitian guard
      G[(size_t)(b0 + b) * 10000 + k] = make_float2(fr[b], fib);
      if (k >= 1 && k <= 4999)
        G[(size_t)(b0 + b) * 10000 + (10000 - k)] = make_float2(fr[b], -fib);
    }
  }
}

// ---------------- inverse stage 1 (Hermitian-halved, LDS-staged) ----------------
// Block = (sig, split). G[sig] cols 0..51 of all 100 rows staged in LDS (41.6 KB),
// then each thread computes a 2 m1 x 2 n2 tile:
// Bi[m1][n2] = (sum_n1 G[100n1+n2] e^{+2pi i n1 m1/100}) * e^{+2pi i n2 m1/10000}.
// Cols 0,50 pre-scaled by 0.5 (col 51 by 0) so i2 is a uniform doubled sum.
// tiles/sig = 50*26 = 1300 (6 splits).
__global__ void k_i1(const float2* __restrict__ G,
                     const float* __restrict__ t100c, const float* __restrict__ t100s,
                     const float* __restrict__ twc, const float* __restrict__ tws,
                     float2* __restrict__ Bi) {
  __shared__ float gs[10400];   // 100 rows x 52 complex (104 floats/row)
  unsigned sig = blockIdx.x;
  const float* gp = (const float*)(G + sig * 10000u);
  for (int i = threadIdx.x; i < 2600; i += 256) {
    int row = i / 26, c4 = i % 26;
    *(float4*)(gs + row * 104 + c4 * 4) = *(const float4*)(gp + row * 200 + c4 * 4);
  }
  __syncthreads();
  unsigned tt = blockIdx.y * 256u + threadIdx.x;
  if (tt >= 1300u) return;
  unsigned m1 = (tt / 26u) * 2u, n2 = (tt % 26u) * 2u;
  float reA[2] = {}, imA[2] = {};   // col n2   for m1, m1+1
  float reB[2] = {}, imB[2] = {};   // col n2+1 for m1, m1+1
#pragma unroll 4
  for (int n1 = 0; n1 < 100; ++n1) {
    const float4 gv = *(const float4*)(gs + n1 * 104 + n2 * 2);  // 2 complex, LDS
    const float2 cv = *(const float2*)(t100c + n1 * 100 + m1);
    const float2 sv = *(const float2*)(t100s + n1 * 100 + m1);
    const float cc[2] = {cv.x, cv.y};
    const float ss[2] = {sv.x, sv.y};
#pragma unroll
    for (int i = 0; i < 2; ++i) {
      reA[i] += gv.x * cc[i] - gv.y * ss[i];
      imA[i] += gv.y * cc[i] + gv.x * ss[i];
      reB[i] += gv.z * cc[i] - gv.w * ss[i];
      imB[i] += gv.w * cc[i] + gv.z * ss[i];
    }
  }
  float w0 = (n2 == 0 || n2 == 50) ? 0.5f : 1.0f;
  float w1 = (n2 == 50) ? 0.0f : 1.0f;   // col 51 unused
#pragma unroll
  for (int i = 0; i < 2; ++i) {
    float cw0 = twc[n2 * 100 + m1 + i],       sw0 = tws[n2 * 100 + m1 + i];
    float cw1 = twc[(n2 + 1) * 100 + m1 + i], sw1 = tws[(n2 + 1) * 100 + m1 + i];
    float4 outv;
    outv.x = (reA[i] * cw0 - imA[i] * sw0) * w0;
    outv.y = (imA[i] * cw0 + reA[i] * sw0) * w0;
    outv.z = (reB[i] * cw1 - imB[i] * sw1) * w1;
    outv.w = (imB[i] * cw1 + reB[i] * sw1) * w1;
    *(float4*)((float*)Bi + (sig * 5200u + (m1 + i) * 52u + n2) * 2) = outv;
  }
}

// ---------------- inverse stage 2 (Hermitian-halved, LDS-staged, real part) ----------------
// Block = (sig, split). Bi[sig] (5200 complex, 41.6 KB) staged; thread tile 2 m1 x 2 m2,
// m2 fastest across lanes. y[m1+100m2] = 2e-4*2*sum_{n2<52} Re(Bi[m1][n2] w^{n2 m2}).
// threads/sig = 50*50 = 2500 (10 splits).
__global__ void k_i2(const float2* __restrict__ Bi,
                     const float* __restrict__ t100c, const float* __restrict__ t100s,
                     float* __restrict__ mol) {
  __shared__ float bs[10400];   // 100 rows x 52 complex
  unsigned sig = blockIdx.x;
  const float* bp = (const float*)Bi + sig * 10400u;
  for (int i = threadIdx.x; i < 2600; i += 256)
    *(float4*)(bs + 4 * i) = *(const float4*)(bp + 4 * i);
  __syncthreads();
  unsigned tt = blockIdx.y * 256u + threadIdx.x;
  if (tt >= 2500u) return;
  unsigned m1 = (tt / 50u) * 2u;   // 50 groups -> m1 = 0..98
  unsigned m2 = (tt % 50u) * 2u;   // 50 groups, fastest
  const float* b0 = bs + m1 * 104u;
  const float* b1 = b0 + 104;
  float re[2][2] = {};
#pragma unroll 4
  for (int jj = 0; jj < 26; ++jj) {
    int n2 = 2 * jj;
    const float4 v0 = *(const float4*)(b0 + 2 * n2);
    const float4 v1 = *(const float4*)(b1 + 2 * n2);
    const float2 c0 = *(const float2*)(t100c + n2 * 100 + m2);
    const float2 s0 = *(const float2*)(t100s + n2 * 100 + m2);
    const float2 c1 = *(const float2*)(t100c + (n2 + 1) * 100 + m2);
    const float2 s1 = *(const float2*)(t100s + (n2 + 1) * 100 + m2);
    const float cc0[2] = {c0.x, c0.y}, ss0[2] = {s0.x, s0.y};
    const float cc1[2] = {c1.x, c1.y}, ss1[2] = {s1.x, s1.y};
#pragma unroll
    for (int j = 0; j < 2; ++j) {
      re[0][j] += v0.x * cc0[j] - v0.y * ss0[j];
      re[1][j] += v1.x * cc0[j] - v1.y * ss0[j];
      re[0][j] += v0.z * cc1[j] - v0.w * ss1[j];
      re[1][j] += v1.z * cc1[j] - v1.w * ss1[j];
    }
  }
#pragma unroll
  for (int i = 0; i < 2; ++i)
#pragma unroll
    for (int j = 0; j < 2; ++j)
      mol[sig * 10000u + (m1 + i) + 100u * (m2 + j)] = re[i][j] * 2e-4f;
}

// ---------------- projection: out[b,p] = sum_d mol[b,d] W[p,d] ; D split into 125 chunks of 80 ----------------
// thread tile: 4 p x 16 b  (1 B LDS per FMA; W-row streams)
__global__ __launch_bounds__(256) void k_proj(const float* __restrict__ mol,
                                              const float* __restrict__ W,
                                              float* __restrict__ part) {
  __shared__ float molS[80 * 64];
  int tid = threadIdx.x;
  int d0 = blockIdx.x * 80;
  for (int i = tid; i < 80 * 64; i += 256)
    molS[i] = mol[(size_t)(i & 63) * 10000 + d0 + (i >> 6)];
  __syncthreads();
  int p0 = (tid & 63) * 4;
  int bh = (tid >> 6) * 16;
  float acc[4][16] = {};
  const float* w0 = W + (size_t)(p0 + 0) * 10000 + d0;
  const float* w1 = W + (size_t)(p0 + 1) * 10000 + d0;
  const float* w2 = W + (size_t)(p0 + 2) * 10000 + d0;
  const float* w3 = W + (size_t)(p0 + 3) * 10000 + d0;
#pragma unroll 4
  for (int dl = 0; dl < 80; ++dl) {
    const float wv[4] = {w0[dl], w1[dl], w2[dl], w3[dl]};
    const float4* m4 = (const float4*)(molS + dl * 64 + bh);
#pragma unroll
    for (int q = 0; q < 4; ++q) {
      float4 mv = m4[q];
#pragma unroll
      for (int pp = 0; pp < 4; ++pp) {
        acc[pp][4 * q + 0] += wv[pp] * mv.x;
        acc[pp][4 * q + 1] += wv[pp] * mv.y;
        acc[pp][4 * q + 2] += wv[pp] * mv.z;
        acc[pp][4 * q + 3] += wv[pp] * mv.w;
      }
    }
  }
#pragma unroll
  for (int b = 0; b < 16; ++b) {
    float4 v = make_float4(acc[0][b], acc[1][b], acc[2][b], acc[3][b]);
    *(float4*)(part + (size_t)blockIdx.x * 16384 + (bh + b) * 256 + p0) = v;
  }
}

// ---------------- reduce partials + bias ----------------
__global__ void k_red(const float* __restrict__ part, const float* __restrict__ bias,
                      float* __restrict__ out) {
  int tid = threadIdx.x;
  int b = blockIdx.x;
  float acc = bias[tid];
#pragma unroll 8
  for (int ch = 0; ch < 125; ++ch)
    acc += part[(size_t)ch * 16384 + b * 256 + tid];
  out[b * 256 + tid] = acc;
}

extern "C" void kernel_launch(void* const* d_in, const int* in_sizes, int n_in,
                              void* d_out, int out_size, void* d_ws, size_t ws_size,
                              hipStream_t stream) {
  const float* atom  = (const float*)d_in[0];   // [10,10000]
  const float* pos   = (const float*)d_in[1];   // [128,10000]
  const float* clo   = (const float*)d_in[2];   // [10000]
  const float* W     = (const float*)d_in[3];   // [256,10000]
  const float* bias  = (const float*)d_in[4];   // [256]
  const float* tmask = (const float*)d_in[5];   // [64,128]
  const float* rmask = (const float*)d_in[6];   // [64,8]
  const int*   aidx  = (const int*)d_in[7];     // [64,128]
  const int*   rpos  = (const int*)d_in[8];     // [64,8,2]
  float* out = (float*)d_out;                   // [64,256]

  char* ws = (char*)d_ws;
  size_t off = 0;
  auto alloc = [&](size_t n) { off = (off + 255) & ~(size_t)255; size_t o = off; off += n; return o; };
  float* t100c = (float*)(ws + alloc(10000 * 4));
  float* t100s = (float*)(ws + alloc(10000 * 4));
  float* twc   = (float*)(ws + alloc(10000 * 4));
  float* tws   = (float*)(ws + alloc(10000 * 4));
  char* regA   = ws + alloc(16777216);          // Bbuf (11.12MB) / Bi (2.66MB) / partials (8.2MB)
  float2* Bbuf = (float2*)regA;
  float2* Bi   = (float2*)regA;                 // Bi overlays Bbuf (f2 done reading before i1 writes)
  float*  part = (float*)regA;
  float2* spec = (float2*)(ws + alloc((size_t)NSIG * FS * 8));
  float2* G    = (float2*)(ws + alloc((size_t)64 * 10000 * 8));
  float*  mol  = (float*)(ws + alloc((size_t)64 * 10000 * 4));

  k_tables<<<dim3(40), dim3(256), 0, stream>>>(t100c, t100s, twc, tws);
  k_f1<<<dim3(NSIG, 5), dim3(256), 0, stream>>>(atom, pos, clo, t100c, t100s, twc, tws, Bbuf);
  k_f2<<<dim3(NSIG, 2, 3), dim3(256), 0, stream>>>(Bbuf, t100c, t100s, spec);
  k_mix<<<dim3(20, 16), dim3(256), 0, stream>>>(spec, tmask, rmask, aidx, rpos, G);
  k_i1<<<dim3(64, 6), dim3(256), 0, stream>>>(G, t100c, t100s, twc, tws, Bi);
  k_i2<<<dim3(64, 10), dim3(256), 0, stream>>>(Bi, t100c, t100s, mol);
  k_proj<<<dim3(125), dim3(256), 0, stream>>>(mol, W, part);
  k_red<<<dim3(64), dim3(256), 0, stream>>>(part, bias, out);
}

// Round 10
// 220.553 us; speedup vs baseline: 1.0824x; 1.0824x over previous
//
#include <hip/hip_runtime.h>

#define PI2 6.28318530717958647692f

// D = 10000 = 100 x 100; F = 5001; signals: 128 pos + 10 atom + 1 closure = 139
#define NSIG 139
#define FS   5120      // spectrum row stride (float2)

// ---------------- twiddle tables ----------------
__global__ void k_tables(float* __restrict__ t100c, float* __restrict__ t100s,
                         float* __restrict__ twc,   float* __restrict__ tws) {
  int idx = blockIdx.x * 256 + threadIdx.x;
  if (idx >= 10000) return;
  int j = idx / 100, m = idx % 100;
  int r1 = (j * m) % 100;
  float a1 = PI2 * (float)r1 * 0.01f;
  float s1, c1; sincosf(a1, &s1, &c1);
  t100c[idx] = c1; t100s[idx] = s1;
  int r2 = (j * m) % 10000;
  float a2 = PI2 * (float)r2 * 0.0001f;
  float s2, c2; sincosf(a2, &s2, &c2);
  twc[idx] = c2; tws[idx] = s2;
}

// ---------------- forward stage 1 (Hermitian-paired, LDS-staged) ----------------
__global__ void k_f1(const float* __restrict__ atom, const float* __restrict__ pos,
                     const float* __restrict__ clo,
                     const float* __restrict__ t100c, const float* __restrict__ t100s,
                     const float* __restrict__ twc, const float* __restrict__ tws,
                     float2* __restrict__ Bbuf) {
  __shared__ float xs[10000];
  unsigned sig = blockIdx.x;
  const float* xb = (sig < 128u) ? (pos + sig * 10000u)
                   : ((sig < 138u) ? (atom + (sig - 128u) * 10000u) : clo);
  for (int i = threadIdx.x; i < 2500; i += 256)
    *(float4*)(xs + 4 * i) = *(const float4*)(xb + 4 * i);
  __syncthreads();
  unsigned tt = blockIdx.y * 256u + threadIdx.x;
  if (tt >= 1275u) return;
  unsigned k1 = tt / 25u, n2 = (tt % 25u) * 4u;
  float ar[4] = {}, as[4] = {};
#pragma unroll 4
  for (int n1 = 0; n1 < 100; ++n1) {
    const float4 xv = *(const float4*)(xs + n1 * 100 + n2);   // LDS, contiguous b128
    const float c = t100c[n1 * 100 + k1];                      // broadcast (L1)
    const float s = t100s[n1 * 100 + k1];
    ar[0] += xv.x * c; as[0] += xv.x * s;
    ar[1] += xv.y * c; as[1] += xv.y * s;
    ar[2] += xv.z * c; as[2] += xv.z * s;
    ar[3] += xv.w * c; as[3] += xv.w * s;
  }
  unsigned rb = (100u - k1) % 100u;
  float2* rowA = Bbuf + sig * 10000u + k1 * 100u + n2;
  float2* rowB = Bbuf + sig * 10000u + rb * 100u + n2;
#pragma unroll
  for (int j = 0; j < 4; ++j) {
    float cwA = twc[(n2 + j) * 100 + k1];
    float swA = tws[(n2 + j) * 100 + k1];
    rowA[j] = make_float2(ar[j] * cwA - as[j] * swA,
                          -(as[j] * cwA + ar[j] * swA));
    float cwB = twc[(n2 + j) * 100 + rb];
    float swB = tws[(n2 + j) * 100 + rb];
    rowB[j] = make_float2(ar[j] * cwB + as[j] * swB,
                          as[j] * cwB - ar[j] * swB);
  }
}

// ---------------- forward stage 2 (LDS-staged) ----------------
__global__ void k_f2(const float2* __restrict__ Bbuf,
                     const float* __restrict__ t100c, const float* __restrict__ t100s,
                     float2* __restrict__ spec) {
  __shared__ float bs[10000];   // 50 rows x 100 complex
  unsigned sig = blockIdx.x, half = blockIdx.y;
  const float* bp = (const float*)(Bbuf + sig * 10000u + half * 5000u);
  for (int i = threadIdx.x; i < 2500; i += 256)
    *(float4*)(bs + 4 * i) = *(const float4*)(bp + 4 * i);
  __syncthreads();
  unsigned tt = blockIdx.z * 256u + threadIdx.x;
  if (tt >= 650u) return;
  unsigned k1l = (tt / 26u) * 2u;   // local row, 25 groups
  unsigned k2 = (tt % 26u) * 2u;    // 26 groups, fastest
  const float* brow0 = bs + k1l * 200u;
  const float* brow1 = brow0 + 200;
  float re[2][2] = {}, im[2][2] = {};
#pragma unroll 4
  for (int n2 = 0; n2 < 100; n2 += 2) {
    const float4 b0 = *(const float4*)(brow0 + 2 * n2);
    const float4 b1 = *(const float4*)(brow1 + 2 * n2);
    const float2 c0 = *(const float2*)(t100c + n2 * 100 + k2);
    const float2 s0 = *(const float2*)(t100s + n2 * 100 + k2);
    const float2 c1 = *(const float2*)(t100c + (n2 + 1) * 100 + k2);
    const float2 s1 = *(const float2*)(t100s + (n2 + 1) * 100 + k2);
    const float cc0[2] = {c0.x, c0.y}, ss0[2] = {s0.x, s0.y};
    const float cc1[2] = {c1.x, c1.y}, ss1[2] = {s1.x, s1.y};
#pragma unroll
    for (int j = 0; j < 2; ++j) {
      re[0][j] += b0.x * cc0[j] + b0.y * ss0[j];
      im[0][j] += b0.y * cc0[j] - b0.x * ss0[j];
      re[1][j] += b1.x * cc0[j] + b1.y * ss0[j];
      im[1][j] += b1.y * cc0[j] - b1.x * ss0[j];
      re[0][j] += b0.z * cc1[j] + b0.w * ss1[j];
      im[0][j] += b0.w * cc1[j] - b0.z * ss1[j];
      re[1][j] += b1.z * cc1[j] + b1.w * ss1[j];
      im[1][j] += b1.w * cc1[j] - b1.z * ss1[j];
    }
  }
  unsigned k1 = half * 50u + k1l;
#pragma unroll
  for (int i = 0; i < 2; ++i)
#pragma unroll
    for (int j = 0; j < 2; ++j) {
      unsigned k = (k1 + i) + 100u * (k2 + j);
      if (k <= 5000u)
        spec[sig * FS + k] = make_float2(re[i][j], im[i][j]);
    }
}

// ---------------- mix: b-tile 2, 640 blocks, serial Fp loads (round-4/6 proven shape) ----------------
__global__ void k_mix(const float2* __restrict__ spec,
                      const float* __restrict__ tmask, const float* __restrict__ rmask,
                      const int* __restrict__ aidx, const int* __restrict__ rpos,
                      float2* __restrict__ G) {
  __shared__ float2 FaS[10][256];
  __shared__ float2 FcS[256];
  __shared__ float tmS[2][128];
  __shared__ int   aiS[2][128];
  __shared__ float rmS[2][8];
  __shared__ int   rpS[2][8][2];
  int tid = threadIdx.x;
  int k = blockIdx.x * 256 + tid;
  int kc = k > 5000 ? 5000 : k;
  int b0 = blockIdx.y * 2;
#pragma unroll
  for (int a = 0; a < 10; ++a) FaS[a][tid] = spec[(128 + a) * FS + kc];
  FcS[tid] = spec[138 * FS + kc];
  for (int i = tid; i < 2 * 128; i += 256) {
    int bb = i >> 7, ss = i & 127;
    tmS[bb][ss] = tmask[(b0 + bb) * 128 + ss];
    aiS[bb][ss] = aidx[(b0 + bb) * 128 + ss];
  }
  if (tid < 16) {
    int bb = tid >> 3, rr = tid & 7;
    rmS[bb][rr] = rmask[(b0 + bb) * 8 + rr];
    rpS[bb][rr][0] = rpos[((b0 + bb) * 8 + rr) * 2 + 0];
    rpS[bb][rr][1] = rpos[((b0 + bb) * 8 + rr) * 2 + 1];
  }
  __syncthreads();
  float fr[2] = {}, fi[2] = {};
#pragma unroll 8
  for (int s = 0; s < 128; ++s) {
    float2 fp = spec[s * FS + kc];   // address-independent across s -> ILP
#pragma unroll
    for (int b = 0; b < 2; ++b) {
      int a = aiS[b][s];
      float tm = tmS[b][s];
      float2 fa = FaS[a][tid];
      float tr = fa.x * fp.x - fa.y * fp.y;
      float ti = fa.x * fp.y + fa.y * fp.x;
      fr[b] += tm * tr;
      fi[b] += tm * ti;
    }
  }
  float2 fc = FcS[tid];
#pragma unroll
  for (int r = 0; r < 8; ++r) {
#pragma unroll
    for (int b = 0; b < 2; ++b) {
      int p0 = rpS[b][r][0], p1 = rpS[b][r][1];
      float rm = rmS[b][r];
      float2 f0 = spec[p0 * FS + kc];
      float2 f1 = spec[p1 * FS + kc];
      float tr = f0.x * f1.x - f0.y * f1.y;
      float ti = f0.x * f1.y + f0.y * f1.x;
      float ur = tr * fc.x - ti * fc.y;
      float ui = tr * fc.y + ti * fc.x;
      fr[b] += rm * ur;
      fi[b] += rm * ui;
    }
  }
  if (k <= 5000) {
#pragma unroll
    for (int b = 0; b < 2; ++b) {
      float fib = (k == 0 || k == 5000) ? 0.0f : fi[b];  // exact Hermitian guard
      G[(size_t)(b0 + b) * 10000 + k] = make_float2(fr[b], fib);
      if (k >= 1 && k <= 4999)
        G[(size_t)(b0 + b) * 10000 + (10000 - k)] = make_float2(fr[b], -fib);
    }
  }
}

// ---------------- inverse stage 1 (Hermitian-halved, LDS-staged) ----------------
__global__ void k_i1(const float2* __restrict__ G,
                     const float* __restrict__ t100c, const float* __restrict__ t100s,
                     const float* __restrict__ twc, const float* __restrict__ tws,
                     float2* __restrict__ Bi) {
  __shared__ float gs[10400];   // 100 rows x 52 complex (104 floats/row)
  unsigned sig = blockIdx.x;
  const float* gp = (const float*)(G + sig * 10000u);
  for (int i = threadIdx.x; i < 2600; i += 256) {
    int row = i / 26, c4 = i % 26;
    *(float4*)(gs + row * 104 + c4 * 4) = *(const float4*)(gp + row * 200 + c4 * 4);
  }
  __syncthreads();
  unsigned tt = blockIdx.y * 256u + threadIdx.x;
  if (tt >= 1300u) return;
  unsigned m1 = (tt / 26u) * 2u, n2 = (tt % 26u) * 2u;
  float reA[2] = {}, imA[2] = {};
  float reB[2] = {}, imB[2] = {};
#pragma unroll 4
  for (int n1 = 0; n1 < 100; ++n1) {
    const float4 gv = *(const float4*)(gs + n1 * 104 + n2 * 2);
    const float2 cv = *(const float2*)(t100c + n1 * 100 + m1);
    const float2 sv = *(const float2*)(t100s + n1 * 100 + m1);
    const float cc[2] = {cv.x, cv.y};
    const float ss[2] = {sv.x, sv.y};
#pragma unroll
    for (int i = 0; i < 2; ++i) {
      reA[i] += gv.x * cc[i] - gv.y * ss[i];
      imA[i] += gv.y * cc[i] + gv.x * ss[i];
      reB[i] += gv.z * cc[i] - gv.w * ss[i];
      imB[i] += gv.w * cc[i] + gv.z * ss[i];
    }
  }
  float w0 = (n2 == 0 || n2 == 50) ? 0.5f : 1.0f;
  float w1 = (n2 == 50) ? 0.0f : 1.0f;
#pragma unroll
  for (int i = 0; i < 2; ++i) {
    float cw0 = twc[n2 * 100 + m1 + i],       sw0 = tws[n2 * 100 + m1 + i];
    float cw1 = twc[(n2 + 1) * 100 + m1 + i], sw1 = tws[(n2 + 1) * 100 + m1 + i];
    float4 outv;
    outv.x = (reA[i] * cw0 - imA[i] * sw0) * w0;
    outv.y = (imA[i] * cw0 + reA[i] * sw0) * w0;
    outv.z = (reB[i] * cw1 - imB[i] * sw1) * w1;
    outv.w = (imB[i] * cw1 + reB[i] * sw1) * w1;
    *(float4*)((float*)Bi + (sig * 5200u + (m1 + i) * 52u + n2) * 2) = outv;
  }
}

// ---------------- inverse stage 2 (Hermitian-halved, LDS-staged, real part) ----------------
__global__ void k_i2(const float2* __restrict__ Bi,
                     const float* __restrict__ t100c, const float* __restrict__ t100s,
                     float* __restrict__ mol) {
  __shared__ float bs[10400];   // 100 rows x 52 complex
  unsigned sig = blockIdx.x;
  const float* bp = (const float*)Bi + sig * 10400u;
  for (int i = threadIdx.x; i < 2600; i += 256)
    *(float4*)(bs + 4 * i) = *(const float4*)(bp + 4 * i);
  __syncthreads();
  unsigned tt = blockIdx.y * 256u + threadIdx.x;
  if (tt >= 2500u) return;
  unsigned m1 = (tt / 50u) * 2u;   // 50 groups -> m1 = 0..98
  unsigned m2 = (tt % 50u) * 2u;   // 50 groups, fastest
  const float* b0 = bs + m1 * 104u;
  const float* b1 = b0 + 104;
  float re[2][2] = {};
#pragma unroll 4
  for (int jj = 0; jj < 26; ++jj) {
    int n2 = 2 * jj;
    const float4 v0 = *(const float4*)(b0 + 2 * n2);
    const float4 v1 = *(const float4*)(b1 + 2 * n2);
    const float2 c0 = *(const float2*)(t100c + n2 * 100 + m2);
    const float2 s0 = *(const float2*)(t100s + n2 * 100 + m2);
    const float2 c1 = *(const float2*)(t100c + (n2 + 1) * 100 + m2);
    const float2 s1 = *(const float2*)(t100s + (n2 + 1) * 100 + m2);
    const float cc0[2] = {c0.x, c0.y}, ss0[2] = {s0.x, s0.y};
    const float cc1[2] = {c1.x, c1.y}, ss1[2] = {s1.x, s1.y};
#pragma unroll
    for (int j = 0; j < 2; ++j) {
      re[0][j] += v0.x * cc0[j] - v0.y * ss0[j];
      re[1][j] += v1.x * cc0[j] - v1.y * ss0[j];
      re[0][j] += v0.z * cc1[j] - v0.w * ss1[j];
      re[1][j] += v1.z * cc1[j] - v1.w * ss1[j];
    }
  }
#pragma unroll
  for (int i = 0; i < 2; ++i)
#pragma unroll
    for (int j = 0; j < 2; ++j)
      mol[sig * 10000u + (m1 + i) + 100u * (m2 + j)] = re[i][j] * 2e-4f;
}

// ---------------- projection: 250 chunks of 40 (round-6 proven) ----------------
__global__ __launch_bounds__(256) void k_proj(const float* __restrict__ mol,
                                              const float* __restrict__ W,
                                              float* __restrict__ part) {
  __shared__ float molS[40 * 64];
  int tid = threadIdx.x;
  int d0 = blockIdx.x * 40;
  for (int i = tid; i < 40 * 64; i += 256)
    molS[i] = mol[(size_t)(i & 63) * 10000 + d0 + (i >> 6)];
  __syncthreads();
  int p0 = (tid & 63) * 4;
  int bh = (tid >> 6) * 16;
  float acc[4][16] = {};
  const float* w0 = W + (size_t)(p0 + 0) * 10000 + d0;
  const float* w1 = W + (size_t)(p0 + 1) * 10000 + d0;
  const float* w2 = W + (size_t)(p0 + 2) * 10000 + d0;
  const float* w3 = W + (size_t)(p0 + 3) * 10000 + d0;
#pragma unroll 4
  for (int dl = 0; dl < 40; ++dl) {
    const float wv[4] = {w0[dl], w1[dl], w2[dl], w3[dl]};
    const float4* m4 = (const float4*)(molS + dl * 64 + bh);
#pragma unroll
    for (int q = 0; q < 4; ++q) {
      float4 mv = m4[q];
#pragma unroll
      for (int pp = 0; pp < 4; ++pp) {
        acc[pp][4 * q + 0] += wv[pp] * mv.x;
        acc[pp][4 * q + 1] += wv[pp] * mv.y;
        acc[pp][4 * q + 2] += wv[pp] * mv.z;
        acc[pp][4 * q + 3] += wv[pp] * mv.w;
      }
    }
  }
#pragma unroll
  for (int b = 0; b < 16; ++b) {
    float4 v = make_float4(acc[0][b], acc[1][b], acc[2][b], acc[3][b]);
    *(float4*)(part + (size_t)blockIdx.x * 16384 + (bh + b) * 256 + p0) = v;
  }
}

// ---------------- reduce partials + bias ----------------
__global__ void k_red(const float* __restrict__ part, const float* __restrict__ bias,
                      float* __restrict__ out) {
  int tid = threadIdx.x;
  int b = blockIdx.x;
  float acc = bias[tid];
#pragma unroll 8
  for (int ch = 0; ch < 250; ++ch)
    acc += part[(size_t)ch * 16384 + b * 256 + tid];
  out[b * 256 + tid] = acc;
}

extern "C" void kernel_launch(void* const* d_in, const int* in_sizes, int n_in,
                              void* d_out, int out_size, void* d_ws, size_t ws_size,
                              hipStream_t stream) {
  const float* atom  = (const float*)d_in[0];   // [10,10000]
  const float* pos   = (const float*)d_in[1];   // [128,10000]
  const float* clo   = (const float*)d_in[2];   // [10000]
  const float* W     = (const float*)d_in[3];   // [256,10000]
  const float* bias  = (const float*)d_in[4];   // [256]
  const float* tmask = (const float*)d_in[5];   // [64,128]
  const float* rmask = (const float*)d_in[6];   // [64,8]
  const int*   aidx  = (const int*)d_in[7];     // [64,128]
  const int*   rpos  = (const int*)d_in[8];     // [64,8,2]
  float* out = (float*)d_out;                   // [64,256]

  char* ws = (char*)d_ws;
  size_t off = 0;
  auto alloc = [&](size_t n) { off = (off + 255) & ~(size_t)255; size_t o = off; off += n; return o; };
  float* t100c = (float*)(ws + alloc(10000 * 4));
  float* t100s = (float*)(ws + alloc(10000 * 4));
  float* twc   = (float*)(ws + alloc(10000 * 4));
  float* tws   = (float*)(ws + alloc(10000 * 4));
  char* regA   = ws + alloc(16777216);          // Bbuf (11.12MB) / Bi (2.66MB) / partials (16.4MB)
  float2* Bbuf = (float2*)regA;
  float2* Bi   = (float2*)regA;                 // Bi overlays Bbuf (f2 done reading before i1 writes)
  float*  part = (float*)regA;
  float2* spec = (float2*)(ws + alloc((size_t)NSIG * FS * 8));
  float2* G    = (float2*)(ws + alloc((size_t)64 * 10000 * 8));
  float*  mol  = (float*)(ws + alloc((size_t)64 * 10000 * 4));

  k_tables<<<dim3(40), dim3(256), 0, stream>>>(t100c, t100s, twc, tws);
  k_f1<<<dim3(NSIG, 5), dim3(256), 0, stream>>>(atom, pos, clo, t100c, t100s, twc, tws, Bbuf);
  k_f2<<<dim3(NSIG, 2, 3), dim3(256), 0, stream>>>(Bbuf, t100c, t100s, spec);
  k_mix<<<dim3(20, 32), dim3(256), 0, stream>>>(spec, tmask, rmask, aidx, rpos, G);
  k_i1<<<dim3(64, 6), dim3(256), 0, stream>>>(G, t100c, t100s, twc, tws, Bi);
  k_i2<<<dim3(64, 10), dim3(256), 0, stream>>>(Bi, t100c, t100s, mol);
  k_proj<<<dim3(250), dim3(256), 0, stream>>>(mol, W, part);
  k_red<<<dim3(64), dim3(256), 0, stream>>>(part, bias, out);
}

// Round 11
// 202.764 us; speedup vs baseline: 1.1773x; 1.0877x over previous
//
#include <hip/hip_runtime.h>

#define PI2 6.28318530717958647692f

// D = 10000 = 100 x 100; F = 5001; signals: 128 pos + 10 atom + 1 closure = 139
#define NSIG 139
#define FS   5120      // spectrum row stride (float2)

// ---------------- twiddle tables ----------------
__global__ void k_tables(float* __restrict__ t100c, float* __restrict__ t100s,
                         float* __restrict__ twc,   float* __restrict__ tws) {
  int idx = blockIdx.x * 256 + threadIdx.x;
  if (idx >= 10000) return;
  int j = idx / 100, m = idx % 100;
  int r1 = (j * m) % 100;
  float a1 = PI2 * (float)r1 * 0.01f;
  float s1, c1; sincosf(a1, &s1, &c1);
  t100c[idx] = c1; t100s[idx] = s1;
  int r2 = (j * m) % 10000;
  float a2 = PI2 * (float)r2 * 0.0001f;
  float s2, c2; sincosf(a2, &s2, &c2);
  twc[idx] = c2; tws[idx] = s2;
}

// ---------------- forward stage 1 (Hermitian-paired, LDS-staged, twiddle recurrence) ----------------
// Inner loop: 1 ds_read_b128 + 8 accum FMA + 4 recurrence FMA, ZERO global loads.
__global__ void k_f1(const float* __restrict__ atom, const float* __restrict__ pos,
                     const float* __restrict__ clo,
                     const float* __restrict__ t100c, const float* __restrict__ t100s,
                     const float* __restrict__ twc, const float* __restrict__ tws,
                     float2* __restrict__ Bbuf) {
  __shared__ float xs[10000];
  unsigned sig = blockIdx.x;
  const float* xb = (sig < 128u) ? (pos + sig * 10000u)
                   : ((sig < 138u) ? (atom + (sig - 128u) * 10000u) : clo);
  for (int i = threadIdx.x; i < 2500; i += 256)
    *(float4*)(xs + 4 * i) = *(const float4*)(xb + 4 * i);
  __syncthreads();
  unsigned tt = blockIdx.y * 256u + threadIdx.x;
  if (tt >= 1275u) return;
  unsigned k1 = tt / 25u, n2 = (tt % 25u) * 4u;
  // cos/sin(2*pi*k1*n1/100) via angle-addition recurrence, theta = 2*pi*k1/100
  float cth = t100c[100 + k1], sth = t100s[100 + k1];
  float c = 1.0f, s = 0.0f;
  float ar[4] = {}, as[4] = {};
#pragma unroll 4
  for (int n1 = 0; n1 < 100; ++n1) {
    const float4 xv = *(const float4*)(xs + n1 * 100 + n2);   // LDS, contiguous b128
    ar[0] += xv.x * c; as[0] += xv.x * s;
    ar[1] += xv.y * c; as[1] += xv.y * s;
    ar[2] += xv.z * c; as[2] += xv.z * s;
    ar[3] += xv.w * c; as[3] += xv.w * s;
    float cn = c * cth - s * sth;
    float sn = s * cth + c * sth;
    c = cn; s = sn;
  }
  unsigned rb = (100u - k1) % 100u;
  float2* rowA = Bbuf + sig * 10000u + k1 * 100u + n2;
  float2* rowB = Bbuf + sig * 10000u + rb * 100u + n2;
#pragma unroll
  for (int j = 0; j < 4; ++j) {
    float cwA = twc[(n2 + j) * 100 + k1];
    float swA = tws[(n2 + j) * 100 + k1];
    rowA[j] = make_float2(ar[j] * cwA - as[j] * swA,
                          -(as[j] * cwA + ar[j] * swA));
    float cwB = twc[(n2 + j) * 100 + rb];
    float swB = tws[(n2 + j) * 100 + rb];
    rowB[j] = make_float2(ar[j] * cwB + as[j] * swB,
                          as[j] * cwB - ar[j] * swB);
  }
}

// ---------------- forward stage 2 (LDS-staged, twiddle recurrence) ----------------
// Two recurrence streams (k2, k2+1); inner loop: 2 ds_read_b128 + 32 accum + 16 rec FMA.
__global__ void k_f2(const float2* __restrict__ Bbuf,
                     const float* __restrict__ t100c, const float* __restrict__ t100s,
                     float2* __restrict__ spec) {
  __shared__ float bs[10000];   // 50 rows x 100 complex
  unsigned sig = blockIdx.x, half = blockIdx.y;
  const float* bp = (const float*)(Bbuf + sig * 10000u + half * 5000u);
  for (int i = threadIdx.x; i < 2500; i += 256)
    *(float4*)(bs + 4 * i) = *(const float4*)(bp + 4 * i);
  __syncthreads();
  unsigned tt = blockIdx.z * 256u + threadIdx.x;
  if (tt >= 650u) return;
  unsigned k1l = (tt / 26u) * 2u;   // local row, 25 groups
  unsigned k2 = (tt % 26u) * 2u;    // 26 groups, fastest
  const float* brow0 = bs + k1l * 200u;
  const float* brow1 = brow0 + 200;
  // streams: A = k2 (theta_A), B = k2+1 (theta_B); value at n2: cos/sin(2*pi*k2*n2/100)
  float cthA = t100c[100 + k2],     sthA = t100s[100 + k2];
  float cthB = t100c[100 + k2 + 1], sthB = t100s[100 + k2 + 1];
  float cA = 1.0f, sA = 0.0f, cB = 1.0f, sB = 0.0f;
  float re[2][2] = {}, im[2][2] = {};
#pragma unroll 4
  for (int n2i = 0; n2i < 100; n2i += 2) {
    const float4 b0 = *(const float4*)(brow0 + 2 * n2i);  // 2 complex of row k1l (LDS)
    const float4 b1 = *(const float4*)(brow1 + 2 * n2i);  // row k1l+1
    // n2i terms (streams at n2i)
    re[0][0] += b0.x * cA + b0.y * sA;  im[0][0] += b0.y * cA - b0.x * sA;
    re[1][0] += b1.x * cA + b1.y * sA;  im[1][0] += b1.y * cA - b1.x * sA;
    re[0][1] += b0.x * cB + b0.y * sB;  im[0][1] += b0.y * cB - b0.x * sB;
    re[1][1] += b1.x * cB + b1.y * sB;  im[1][1] += b1.y * cB - b1.x * sB;
    // advance to n2i+1
    float cA1 = cA * cthA - sA * sthA, sA1 = sA * cthA + cA * sthA;
    float cB1 = cB * cthB - sB * sthB, sB1 = sB * cthB + cB * sthB;
    // n2i+1 terms
    re[0][0] += b0.z * cA1 + b0.w * sA1;  im[0][0] += b0.w * cA1 - b0.z * sA1;
    re[1][0] += b1.z * cA1 + b1.w * sA1;  im[1][0] += b1.w * cA1 - b1.z * sA1;
    re[0][1] += b0.z * cB1 + b0.w * sB1;  im[0][1] += b0.w * cB1 - b0.z * sB1;
    re[1][1] += b1.z * cB1 + b1.w * sB1;  im[1][1] += b1.w * cB1 - b1.z * sB1;
    // advance to n2i+2
    cA = cA1 * cthA - sA1 * sthA; sA = sA1 * cthA + cA1 * sthA;
    cB = cB1 * cthB - sB1 * sthB; sB = sB1 * cthB + cB1 * sthB;
  }
  unsigned k1 = half * 50u + k1l;
#pragma unroll
  for (int i = 0; i < 2; ++i)
#pragma unroll
    for (int j = 0; j < 2; ++j) {
      unsigned k = (k1 + i) + 100u * (k2 + j);
      if (k <= 5000u)
        spec[sig * FS + k] = make_float2(re[i][j], im[i][j]);
    }
}

// ---------------- mix: b-tile 2, 640 blocks, serial Fp loads (round-10 proven shape) ----------------
__global__ void k_mix(const float2* __restrict__ spec,
                      const float* __restrict__ tmask, const float* __restrict__ rmask,
                      const int* __restrict__ aidx, const int* __restrict__ rpos,
                      float2* __restrict__ G) {
  __shared__ float2 FaS[10][256];
  __shared__ float2 FcS[256];
  __shared__ float tmS[2][128];
  __shared__ int   aiS[2][128];
  __shared__ float rmS[2][8];
  __shared__ int   rpS[2][8][2];
  int tid = threadIdx.x;
  int k = blockIdx.x * 256 + tid;
  int kc = k > 5000 ? 5000 : k;
  int b0 = blockIdx.y * 2;
#pragma unroll
  for (int a = 0; a < 10; ++a) FaS[a][tid] = spec[(128 + a) * FS + kc];
  FcS[tid] = spec[138 * FS + kc];
  for (int i = tid; i < 2 * 128; i += 256) {
    int bb = i >> 7, ss = i & 127;
    tmS[bb][ss] = tmask[(b0 + bb) * 128 + ss];
    aiS[bb][ss] = aidx[(b0 + bb) * 128 + ss];
  }
  if (tid < 16) {
    int bb = tid >> 3, rr = tid & 7;
    rmS[bb][rr] = rmask[(b0 + bb) * 8 + rr];
    rpS[bb][rr][0] = rpos[((b0 + bb) * 8 + rr) * 2 + 0];
    rpS[bb][rr][1] = rpos[((b0 + bb) * 8 + rr) * 2 + 1];
  }
  __syncthreads();
  float fr[2] = {}, fi[2] = {};
#pragma unroll 8
  for (int s = 0; s < 128; ++s) {
    float2 fp = spec[s * FS + kc];   // address-independent across s -> ILP
#pragma unroll
    for (int b = 0; b < 2; ++b) {
      int a = aiS[b][s];
      float tm = tmS[b][s];
      float2 fa = FaS[a][tid];
      float tr = fa.x * fp.x - fa.y * fp.y;
      float ti = fa.x * fp.y + fa.y * fp.x;
      fr[b] += tm * tr;
      fi[b] += tm * ti;
    }
  }
  float2 fc = FcS[tid];
#pragma unroll
  for (int r = 0; r < 8; ++r) {
#pragma unroll
    for (int b = 0; b < 2; ++b) {
      int p0 = rpS[b][r][0], p1 = rpS[b][r][1];
      float rm = rmS[b][r];
      float2 f0 = spec[p0 * FS + kc];
      float2 f1 = spec[p1 * FS + kc];
      float tr = f0.x * f1.x - f0.y * f1.y;
      float ti = f0.x * f1.y + f0.y * f1.x;
      float ur = tr * fc.x - ti * fc.y;
      float ui = tr * fc.y + ti * fc.x;
      fr[b] += rm * ur;
      fi[b] += rm * ui;
    }
  }
  if (k <= 5000) {
#pragma unroll
    for (int b = 0; b < 2; ++b) {
      float fib = (k == 0 || k == 5000) ? 0.0f : fi[b];  // exact Hermitian guard
      G[(size_t)(b0 + b) * 10000 + k] = make_float2(fr[b], fib);
      if (k >= 1 && k <= 4999)
        G[(size_t)(b0 + b) * 10000 + (10000 - k)] = make_float2(fr[b], -fib);
    }
  }
}

// ---------------- inverse stage 1 (Hermitian-halved, LDS-staged, twiddle recurrence) ----------------
// Two streams (m1, m1+1); inner loop: 1 ds_read_b128 + 16 accum + 8 rec FMA, zero global loads.
__global__ void k_i1(const float2* __restrict__ G,
                     const float* __restrict__ t100c, const float* __restrict__ t100s,
                     const float* __restrict__ twc, const float* __restrict__ tws,
                     float2* __restrict__ Bi) {
  __shared__ float gs[10400];   // 100 rows x 52 complex (104 floats/row)
  unsigned sig = blockIdx.x;
  const float* gp = (const float*)(G + sig * 10000u);
  for (int i = threadIdx.x; i < 2600; i += 256) {
    int row = i / 26, c4 = i % 26;
    *(float4*)(gs + row * 104 + c4 * 4) = *(const float4*)(gp + row * 200 + c4 * 4);
  }
  __syncthreads();
  unsigned tt = blockIdx.y * 256u + threadIdx.x;
  if (tt >= 1300u) return;
  unsigned m1 = (tt / 26u) * 2u, n2 = (tt % 26u) * 2u;
  // streams: value at n1 = cos/sin(2*pi*m1*n1/100); inverse sign handled in accum (+s terms)
  float cthA = t100c[100 + m1],     sthA = t100s[100 + m1];
  float cthB = t100c[100 + m1 + 1], sthB = t100s[100 + m1 + 1];
  float cA = 1.0f, sA = 0.0f, cB = 1.0f, sB = 0.0f;
  float reA[2] = {}, imA[2] = {};   // col n2   for m1, m1+1
  float reB[2] = {}, imB[2] = {};   // col n2+1 for m1, m1+1
#pragma unroll 4
  for (int n1 = 0; n1 < 100; ++n1) {
    const float4 gv = *(const float4*)(gs + n1 * 104 + n2 * 2);  // 2 complex, LDS
    reA[0] += gv.x * cA - gv.y * sA;  imA[0] += gv.y * cA + gv.x * sA;
    reB[0] += gv.z * cA - gv.w * sA;  imB[0] += gv.w * cA + gv.z * sA;
    reA[1] += gv.x * cB - gv.y * sB;  imA[1] += gv.y * cB + gv.x * sB;
    reB[1] += gv.z * cB - gv.w * sB;  imB[1] += gv.w * cB + gv.z * sB;
    float cA1 = cA * cthA - sA * sthA, sA1 = sA * cthA + cA * sthA;
    float cB1 = cB * cthB - sB * sthB, sB1 = sB * cthB + cB * sthB;
    cA = cA1; sA = sA1; cB = cB1; sB = sB1;
  }
  float w0 = (n2 == 0 || n2 == 50) ? 0.5f : 1.0f;
  float w1 = (n2 == 50) ? 0.0f : 1.0f;
#pragma unroll
  for (int i = 0; i < 2; ++i) {
    float cw0 = twc[n2 * 100 + m1 + i],       sw0 = tws[n2 * 100 + m1 + i];
    float cw1 = twc[(n2 + 1) * 100 + m1 + i], sw1 = tws[(n2 + 1) * 100 + m1 + i];
    float4 outv;
    outv.x = (reA[i] * cw0 - imA[i] * sw0) * w0;
    outv.y = (imA[i] * cw0 + reA[i] * sw0) * w0;
    outv.z = (reB[i] * cw1 - imB[i] * sw1) * w1;
    outv.w = (imB[i] * cw1 + reB[i] * sw1) * w1;
    *(float4*)((float*)Bi + (sig * 5200u + (m1 + i) * 52u + n2) * 2) = outv;
  }
}

// ---------------- inverse stage 2 (Hermitian-halved, LDS-staged, twiddle recurrence) ----------------
// Two streams (m2, m2+1), advancing by theta per n2 step; zero inner global loads.
__global__ void k_i2(const float2* __restrict__ Bi,
                     const float* __restrict__ t100c, const float* __restrict__ t100s,
                     float* __restrict__ mol) {
  __shared__ float bs[10400];   // 100 rows x 52 complex
  unsigned sig = blockIdx.x;
  const float* bp = (const float*)Bi + sig * 10400u;
  for (int i = threadIdx.x; i < 2600; i += 256)
    *(float4*)(bs + 4 * i) = *(const float4*)(bp + 4 * i);
  __syncthreads();
  unsigned tt = blockIdx.y * 256u + threadIdx.x;
  if (tt >= 2500u) return;
  unsigned m1 = (tt / 50u) * 2u;   // 50 groups -> m1 = 0..98
  unsigned m2 = (tt % 50u) * 2u;   // 50 groups, fastest
  const float* b0 = bs + m1 * 104u;
  const float* b1 = b0 + 104;
  // streams: value at n2 = cos/sin(2*pi*m2*n2/100)
  float cthA = t100c[100 + m2],     sthA = t100s[100 + m2];
  float cthB = t100c[100 + m2 + 1], sthB = t100s[100 + m2 + 1];
  float cA = 1.0f, sA = 0.0f, cB = 1.0f, sB = 0.0f;
  float re[2][2] = {};
#pragma unroll 4
  for (int jj = 0; jj < 26; ++jj) {
    int n2 = 2 * jj;
    const float4 v0 = *(const float4*)(b0 + 2 * n2);
    const float4 v1 = *(const float4*)(b1 + 2 * n2);
    // n2 terms
    re[0][0] += v0.x * cA - v0.y * sA;
    re[1][0] += v1.x * cA - v1.y * sA;
    re[0][1] += v0.x * cB - v0.y * sB;
    re[1][1] += v1.x * cB - v1.y * sB;
    // advance to n2+1
    float cA1 = cA * cthA - sA * sthA, sA1 = sA * cthA + cA * sthA;
    float cB1 = cB * cthB - sB * sthB, sB1 = sB * cthB + cB * sthB;
    // n2+1 terms
    re[0][0] += v0.z * cA1 - v0.w * sA1;
    re[1][0] += v1.z * cA1 - v1.w * sA1;
    re[0][1] += v0.z * cB1 - v0.w * sB1;
    re[1][1] += v1.z * cB1 - v1.w * sB1;
    // advance to n2+2
    cA = cA1 * cthA - sA1 * sthA; sA = sA1 * cthA + cA1 * sthA;
    cB = cB1 * cthB - sB1 * sthB; sB = sB1 * cthB + cB1 * sthB;
  }
#pragma unroll
  for (int i = 0; i < 2; ++i)
#pragma unroll
    for (int j = 0; j < 2; ++j)
      mol[sig * 10000u + (m1 + i) + 100u * (m2 + j)] = re[i][j] * 2e-4f;
}

// ---------------- projection: 250 chunks of 40 (round-6 proven) ----------------
__global__ __launch_bounds__(256) void k_proj(const float* __restrict__ mol,
                                              const float* __restrict__ W,
                                              float* __restrict__ part) {
  __shared__ float molS[40 * 64];
  int tid = threadIdx.x;
  int d0 = blockIdx.x * 40;
  for (int i = tid; i < 40 * 64; i += 256)
    molS[i] = mol[(size_t)(i & 63) * 10000 + d0 + (i >> 6)];
  __syncthreads();
  int p0 = (tid & 63) * 4;
  int bh = (tid >> 6) * 16;
  float acc[4][16] = {};
  const float* w0 = W + (size_t)(p0 + 0) * 10000 + d0;
  const float* w1 = W + (size_t)(p0 + 1) * 10000 + d0;
  const float* w2 = W + (size_t)(p0 + 2) * 10000 + d0;
  const float* w3 = W + (size_t)(p0 + 3) * 10000 + d0;
#pragma unroll 4
  for (int dl = 0; dl < 40; ++dl) {
    const float wv[4] = {w0[dl], w1[dl], w2[dl], w3[dl]};
    const float4* m4 = (const float4*)(molS + dl * 64 + bh);
#pragma unroll
    for (int q = 0; q < 4; ++q) {
      float4 mv = m4[q];
#pragma unroll
      for (int pp = 0; pp < 4; ++pp) {
        acc[pp][4 * q + 0] += wv[pp] * mv.x;
        acc[pp][4 * q + 1] += wv[pp] * mv.y;
        acc[pp][4 * q + 2] += wv[pp] * mv.z;
        acc[pp][4 * q + 3] += wv[pp] * mv.w;
      }
    }
  }
#pragma unroll
  for (int b = 0; b < 16; ++b) {
    float4 v = make_float4(acc[0][b], acc[1][b], acc[2][b], acc[3][b]);
    *(float4*)(part + (size_t)blockIdx.x * 16384 + (bh + b) * 256 + p0) = v;
  }
}

// ---------------- reduce partials + bias ----------------
__global__ void k_red(const float* __restrict__ part, const float* __restrict__ bias,
                      float* __restrict__ out) {
  int tid = threadIdx.x;
  int b = blockIdx.x;
  float acc = bias[tid];
#pragma unroll 8
  for (int ch = 0; ch < 250; ++ch)
    acc += part[(size_t)ch * 16384 + b * 256 + tid];
  out[b * 256 + tid] = acc;
}

extern "C" void kernel_launch(void* const* d_in, const int* in_sizes, int n_in,
                              void* d_out, int out_size, void* d_ws, size_t ws_size,
                              hipStream_t stream) {
  const float* atom  = (const float*)d_in[0];   // [10,10000]
  const float* pos   = (const float*)d_in[1];   // [128,10000]
  const float* clo   = (const float*)d_in[2];   // [10000]
  const float* W     = (const float*)d_in[3];   // [256,10000]
  const float* bias  = (const float*)d_in[4];   // [256]
  const float* tmask = (const float*)d_in[5];   // [64,128]
  const float* rmask = (const float*)d_in[6];   // [64,8]
  const int*   aidx  = (const int*)d_in[7];     // [64,128]
  const int*   rpos  = (const int*)d_in[8];     // [64,8,2]
  float* out = (float*)d_out;                   // [64,256]

  char* ws = (char*)d_ws;
  size_t off = 0;
  auto alloc = [&](size_t n) { off = (off + 255) & ~(size_t)255; size_t o = off; off += n; return o; };
  float* t100c = (float*)(ws + alloc(10000 * 4));
  float* t100s = (float*)(ws + alloc(10000 * 4));
  float* twc   = (float*)(ws + alloc(10000 * 4));
  float* tws   = (float*)(ws + alloc(10000 * 4));
  char* regA   = ws + alloc(16777216);          // Bbuf (11.12MB) / Bi (2.66MB) / partials (16.4MB)
  float2* Bbuf = (float2*)regA;
  float2* Bi   = (float2*)regA;                 // Bi overlays Bbuf (f2 done reading before i1 writes)
  float*  part = (float*)regA;
  float2* spec = (float2*)(ws + alloc((size_t)NSIG * FS * 8));
  float2* G    = (float2*)(ws + alloc((size_t)64 * 10000 * 8));
  float*  mol  = (float*)(ws + alloc((size_t)64 * 10000 * 4));

  k_tables<<<dim3(40), dim3(256), 0, stream>>>(t100c, t100s, twc, tws);
  k_f1<<<dim3(NSIG, 5), dim3(256), 0, stream>>>(atom, pos, clo, t100c, t100s, twc, tws, Bbuf);
  k_f2<<<dim3(NSIG, 2, 3), dim3(256), 0, stream>>>(Bbuf, t100c, t100s, spec);
  k_mix<<<dim3(20, 32), dim3(256), 0, stream>>>(spec, tmask, rmask, aidx, rpos, G);
  k_i1<<<dim3(64, 6), dim3(256), 0, stream>>>(G, t100c, t100s, twc, tws, Bi);
  k_i2<<<dim3(64, 10), dim3(256), 0, stream>>>(Bi, t100c, t100s, mol);
  k_proj<<<dim3(250), dim3(256), 0, stream>>>(mol, W, part);
  k_red<<<dim3(64), dim3(256), 0, stream>>>(part, bias, out);
}

// Round 12
// 199.445 us; speedup vs baseline: 1.1969x; 1.0166x over previous
//
#include <hip/hip_runtime.h>

#define PI2 6.28318530717958647692f

// D = 10000 = 100 x 100; F = 5001; signals: 128 pos + 10 atom + 1 closure = 139
#define NSIG 139
#define FS   5120      // spectrum row stride (float2)

// ---------------- fused forward (f1+f2), Hermitian-paired, LDS-resident ----------------
// Block = (sig, quarter q). k1 range: q*13 .. min(q*13+12, 50).
// Phase 1: stage x (40 KB LDS); per-tile DFT100 over n1 with twiddle recurrence,
//          Hermitian pairing gives rows k1 and (100-k1)%100; post-twiddle results in regs.
// Phase 2: write the 2*nk1 B-rows into LDS (overlays xs; 26*200 floats = 20.8 KB < 40 KB).
// Phase 3: f2 column-DFT from LDS rows, k2 in [0,52), write spec (k<=5000 guard).
// All trig inline: products (n2+j)*k1 <= 99*99 < 10000 -> exact small angles.
__global__ __launch_bounds__(256) void k_fwd(
                     const float* __restrict__ atom, const float* __restrict__ pos,
                     const float* __restrict__ clo, float2* __restrict__ spec) {
  __shared__ float xs[10000];   // phase1: x signal; phase3: B rows (row stride 200 floats)
  unsigned sig = blockIdx.x, q = blockIdx.y;
  unsigned k1base = q * 13u;
  unsigned nk1 = (k1base + 13u <= 51u) ? 13u : (51u - k1base);   // q=3 -> 12 (k1 39..50)
  const float* xb = (sig < 128u) ? (pos + sig * 10000u)
                   : ((sig < 138u) ? (atom + (sig - 128u) * 10000u) : clo);
  int tid = threadIdx.x;
  for (int i = tid; i < 2500; i += 256)
    *(float4*)(xs + 4 * i) = *(const float4*)(xb + 4 * i);
  __syncthreads();

  // ---- phase 1: up to 2 tiles/thread, results held in registers ----
  float resA[2][8], resB[2][8];
  unsigned tk1l[2], tn2[2];
  bool have[2];
  unsigned ntile1 = nk1 * 25u;
#pragma unroll
  for (int r = 0; r < 2; ++r) {
    unsigned t = r * 256u + tid;
    have[r] = (t < ntile1);
    if (!have[r]) continue;
    unsigned k1l = t / 25u, n2 = (t % 25u) * 4u;
    unsigned k1 = k1base + k1l;
    tk1l[r] = k1l; tn2[r] = n2;
    float cth, sth;
    __sincosf(PI2 * (float)k1 * 0.01f, &sth, &cth);
    float c = 1.0f, s = 0.0f;
    float ar[4] = {}, as[4] = {};
#pragma unroll 4
    for (int n1 = 0; n1 < 100; ++n1) {
      const float4 xv = *(const float4*)(xs + n1 * 100 + n2);
      ar[0] += xv.x * c; as[0] += xv.x * s;
      ar[1] += xv.y * c; as[1] += xv.y * s;
      ar[2] += xv.z * c; as[2] += xv.z * s;
      ar[3] += xv.w * c; as[3] += xv.w * s;
      float cn = c * cth - s * sth;
      float sn = s * cth + c * sth;
      c = cn; s = sn;
    }
    unsigned rb = (100u - k1) % 100u;
#pragma unroll
    for (int j = 0; j < 4; ++j) {
      float swA, cwA, swB, cwB;
      __sincosf(PI2 * (float)((n2 + j) * k1) * 1e-4f, &swA, &cwA);
      __sincosf(PI2 * (float)((n2 + j) * rb) * 1e-4f, &swB, &cwB);
      resA[r][2 * j + 0] = ar[j] * cwA - as[j] * swA;
      resA[r][2 * j + 1] = -(as[j] * cwA + ar[j] * swA);
      resB[r][2 * j + 0] = ar[j] * cwB + as[j] * swB;
      resB[r][2 * j + 1] = as[j] * cwB - ar[j] * swB;
    }
  }
  __syncthreads();   // all xs reads complete

  // ---- phase 2: write B rows into LDS (overlay xs). local row rA=k1l, rB=nk1+k1l ----
#pragma unroll
  for (int r = 0; r < 2; ++r) {
    if (!have[r]) continue;
    float* pA = xs + tk1l[r] * 200u + tn2[r] * 2u;
    float* pB = xs + (nk1 + tk1l[r]) * 200u + tn2[r] * 2u;
    *(float4*)(pA + 0) = make_float4(resA[r][0], resA[r][1], resA[r][2], resA[r][3]);
    *(float4*)(pA + 4) = make_float4(resA[r][4], resA[r][5], resA[r][6], resA[r][7]);
    *(float4*)(pB + 0) = make_float4(resB[r][0], resB[r][1], resB[r][2], resB[r][3]);
    *(float4*)(pB + 4) = make_float4(resB[r][4], resB[r][5], resB[r][6], resB[r][7]);
  }
  __syncthreads();

  // ---- phase 3: f2 from LDS. tiles: (2*nk1 rows) x 26 k2-pairs ----
  unsigned nrow = 2u * nk1;
  unsigned ntile3 = nrow * 26u;
  for (unsigned t = tid; t < ntile3; t += 256u) {
    unsigned lr = t / 26u, k2 = (t % 26u) * 2u;
    unsigned gk1 = (lr < nk1) ? (k1base + lr) : ((100u - (k1base + (lr - nk1))) % 100u);
    const float* brow = xs + lr * 200u;
    float cthA, sthA, cthB, sthB;
    __sincosf(PI2 * (float)k2 * 0.01f, &sthA, &cthA);
    __sincosf(PI2 * (float)(k2 + 1) * 0.01f, &sthB, &cthB);
    float cA = 1.0f, sA = 0.0f, cB = 1.0f, sB = 0.0f;
    float reA = 0.f, imA = 0.f, reB = 0.f, imB = 0.f;
#pragma unroll 4
    for (int n2i = 0; n2i < 100; n2i += 2) {
      const float4 b0 = *(const float4*)(brow + 2 * n2i);   // 2 complex (LDS)
      reA += b0.x * cA + b0.y * sA;  imA += b0.y * cA - b0.x * sA;
      reB += b0.x * cB + b0.y * sB;  imB += b0.y * cB - b0.x * sB;
      float cA1 = cA * cthA - sA * sthA, sA1 = sA * cthA + cA * sthA;
      float cB1 = cB * cthB - sB * sthB, sB1 = sB * cthB + cB * sthB;
      reA += b0.z * cA1 + b0.w * sA1;  imA += b0.w * cA1 - b0.z * sA1;
      reB += b0.z * cB1 + b0.w * sB1;  imB += b0.w * cB1 - b0.z * sB1;
      cA = cA1 * cthA - sA1 * sthA; sA = sA1 * cthA + cA1 * sthA;
      cB = cB1 * cthB - sB1 * sthB; sB = sB1 * cthB + cB1 * sthB;
    }
    unsigned kA = gk1 + 100u * k2;
    unsigned kB = gk1 + 100u * (k2 + 1);
    if (kA <= 5000u) spec[sig * FS + kA] = make_float2(reA, imA);
    if (kB <= 5000u) spec[sig * FS + kB] = make_float2(reB, imB);
  }
}

// ---------------- mix: b-tile 2, 640 blocks, serial Fp loads (round-10 proven shape) ----------------
__global__ void k_mix(const float2* __restrict__ spec,
                      const float* __restrict__ tmask, const float* __restrict__ rmask,
                      const int* __restrict__ aidx, const int* __restrict__ rpos,
                      float2* __restrict__ G) {
  __shared__ float2 FaS[10][256];
  __shared__ float2 FcS[256];
  __shared__ float tmS[2][128];
  __shared__ int   aiS[2][128];
  __shared__ float rmS[2][8];
  __shared__ int   rpS[2][8][2];
  int tid = threadIdx.x;
  int k = blockIdx.x * 256 + tid;
  int kc = k > 5000 ? 5000 : k;
  int b0 = blockIdx.y * 2;
#pragma unroll
  for (int a = 0; a < 10; ++a) FaS[a][tid] = spec[(128 + a) * FS + kc];
  FcS[tid] = spec[138 * FS + kc];
  for (int i = tid; i < 2 * 128; i += 256) {
    int bb = i >> 7, ss = i & 127;
    tmS[bb][ss] = tmask[(b0 + bb) * 128 + ss];
    aiS[bb][ss] = aidx[(b0 + bb) * 128 + ss];
  }
  if (tid < 16) {
    int bb = tid >> 3, rr = tid & 7;
    rmS[bb][rr] = rmask[(b0 + bb) * 8 + rr];
    rpS[bb][rr][0] = rpos[((b0 + bb) * 8 + rr) * 2 + 0];
    rpS[bb][rr][1] = rpos[((b0 + bb) * 8 + rr) * 2 + 1];
  }
  __syncthreads();
  float fr[2] = {}, fi[2] = {};
#pragma unroll 8
  for (int s = 0; s < 128; ++s) {
    float2 fp = spec[s * FS + kc];   // address-independent across s -> ILP
#pragma unroll
    for (int b = 0; b < 2; ++b) {
      int a = aiS[b][s];
      float tm = tmS[b][s];
      float2 fa = FaS[a][tid];
      float tr = fa.x * fp.x - fa.y * fp.y;
      float ti = fa.x * fp.y + fa.y * fp.x;
      fr[b] += tm * tr;
      fi[b] += tm * ti;
    }
  }
  float2 fc = FcS[tid];
#pragma unroll
  for (int r = 0; r < 8; ++r) {
#pragma unroll
    for (int b = 0; b < 2; ++b) {
      int p0 = rpS[b][r][0], p1 = rpS[b][r][1];
      float rm = rmS[b][r];
      float2 f0 = spec[p0 * FS + kc];
      float2 f1 = spec[p1 * FS + kc];
      float tr = f0.x * f1.x - f0.y * f1.y;
      float ti = f0.x * f1.y + f0.y * f1.x;
      float ur = tr * fc.x - ti * fc.y;
      float ui = tr * fc.y + ti * fc.x;
      fr[b] += rm * ur;
      fi[b] += rm * ui;
    }
  }
  if (k <= 5000) {
#pragma unroll
    for (int b = 0; b < 2; ++b) {
      float fib = (k == 0 || k == 5000) ? 0.0f : fi[b];  // exact Hermitian guard
      G[(size_t)(b0 + b) * 10000 + k] = make_float2(fr[b], fib);
      if (k >= 1 && k <= 4999)
        G[(size_t)(b0 + b) * 10000 + (10000 - k)] = make_float2(fr[b], -fib);
    }
  }
}

// ---------------- inverse stage 1 (Hermitian-halved, LDS-staged, twiddle recurrence, inline trig) ----------------
__global__ void k_i1(const float2* __restrict__ G, float2* __restrict__ Bi) {
  __shared__ float gs[10400];   // 100 rows x 52 complex (104 floats/row)
  unsigned sig = blockIdx.x;
  const float* gp = (const float*)(G + sig * 10000u);
  for (int i = threadIdx.x; i < 2600; i += 256) {
    int row = i / 26, c4 = i % 26;
    *(float4*)(gs + row * 104 + c4 * 4) = *(const float4*)(gp + row * 200 + c4 * 4);
  }
  __syncthreads();
  unsigned tt = blockIdx.y * 256u + threadIdx.x;
  if (tt >= 1300u) return;
  unsigned m1 = (tt / 26u) * 2u, n2 = (tt % 26u) * 2u;
  float cthA, sthA, cthB, sthB;
  __sincosf(PI2 * (float)m1 * 0.01f, &sthA, &cthA);
  __sincosf(PI2 * (float)(m1 + 1) * 0.01f, &sthB, &cthB);
  float cA = 1.0f, sA = 0.0f, cB = 1.0f, sB = 0.0f;
  float reA[2] = {}, imA[2] = {};   // col n2   for m1, m1+1
  float reB[2] = {}, imB[2] = {};   // col n2+1 for m1, m1+1
#pragma unroll 4
  for (int n1 = 0; n1 < 100; ++n1) {
    const float4 gv = *(const float4*)(gs + n1 * 104 + n2 * 2);  // 2 complex, LDS
    reA[0] += gv.x * cA - gv.y * sA;  imA[0] += gv.y * cA + gv.x * sA;
    reB[0] += gv.z * cA - gv.w * sA;  imB[0] += gv.w * cA + gv.z * sA;
    reA[1] += gv.x * cB - gv.y * sB;  imA[1] += gv.y * cB + gv.x * sB;
    reB[1] += gv.z * cB - gv.w * sB;  imB[1] += gv.w * cB + gv.z * sB;
    float cA1 = cA * cthA - sA * sthA, sA1 = sA * cthA + cA * sthA;
    float cB1 = cB * cthB - sB * sthB, sB1 = sB * cthB + cB * sthB;
    cA = cA1; sA = sA1; cB = cB1; sB = sB1;
  }
  float w0 = (n2 == 0 || n2 == 50) ? 0.5f : 1.0f;
  float w1 = (n2 == 50) ? 0.0f : 1.0f;
#pragma unroll
  for (int i = 0; i < 2; ++i) {
    float sw0, cw0, sw1, cw1;
    __sincosf(PI2 * (float)(n2 * (m1 + i)) * 1e-4f, &sw0, &cw0);
    __sincosf(PI2 * (float)((n2 + 1) * (m1 + i)) * 1e-4f, &sw1, &cw1);
    float4 outv;
    outv.x = (reA[i] * cw0 - imA[i] * sw0) * w0;
    outv.y = (imA[i] * cw0 + reA[i] * sw0) * w0;
    outv.z = (reB[i] * cw1 - imB[i] * sw1) * w1;
    outv.w = (imB[i] * cw1 + reB[i] * sw1) * w1;
    *(float4*)((float*)Bi + (sig * 5200u + (m1 + i) * 52u + n2) * 2) = outv;
  }
}

// ---------------- inverse stage 2 (Hermitian-halved, LDS-staged, twiddle recurrence, inline trig) ----------------
__global__ void k_i2(const float2* __restrict__ Bi, float* __restrict__ mol) {
  __shared__ float bs[10400];   // 100 rows x 52 complex
  unsigned sig = blockIdx.x;
  const float* bp = (const float*)Bi + sig * 10400u;
  for (int i = threadIdx.x; i < 2600; i += 256)
    *(float4*)(bs + 4 * i) = *(const float4*)(bp + 4 * i);
  __syncthreads();
  unsigned tt = blockIdx.y * 256u + threadIdx.x;
  if (tt >= 2500u) return;
  unsigned m1 = (tt / 50u) * 2u;   // 50 groups -> m1 = 0..98
  unsigned m2 = (tt % 50u) * 2u;   // 50 groups, fastest
  const float* b0 = bs + m1 * 104u;
  const float* b1 = b0 + 104;
  float cthA, sthA, cthB, sthB;
  __sincosf(PI2 * (float)m2 * 0.01f, &sthA, &cthA);
  __sincosf(PI2 * (float)(m2 + 1) * 0.01f, &sthB, &cthB);
  float cA = 1.0f, sA = 0.0f, cB = 1.0f, sB = 0.0f;
  float re[2][2] = {};
#pragma unroll 4
  for (int jj = 0; jj < 26; ++jj) {
    int n2 = 2 * jj;
    const float4 v0 = *(const float4*)(b0 + 2 * n2);
    const float4 v1 = *(const float4*)(b1 + 2 * n2);
    re[0][0] += v0.x * cA - v0.y * sA;
    re[1][0] += v1.x * cA - v1.y * sA;
    re[0][1] += v0.x * cB - v0.y * sB;
    re[1][1] += v1.x * cB - v1.y * sB;
    float cA1 = cA * cthA - sA * sthA, sA1 = sA * cthA + cA * sthA;
    float cB1 = cB * cthB - sB * sthB, sB1 = sB * cthB + cB * sthB;
    re[0][0] += v0.z * cA1 - v0.w * sA1;
    re[1][0] += v1.z * cA1 - v1.w * sA1;
    re[0][1] += v0.z * cB1 - v0.w * sB1;
    re[1][1] += v1.z * cB1 - v1.w * sB1;
    cA = cA1 * cthA - sA1 * sthA; sA = sA1 * cthA + cA1 * sthA;
    cB = cB1 * cthB - sB1 * sthB; sB = sB1 * cthB + cB1 * sthB;
  }
#pragma unroll
  for (int i = 0; i < 2; ++i)
#pragma unroll
    for (int j = 0; j < 2; ++j)
      mol[sig * 10000u + (m1 + i) + 100u * (m2 + j)] = re[i][j] * 2e-4f;
}

// ---------------- projection: 250 chunks of 40 (round-6 proven) ----------------
__global__ __launch_bounds__(256) void k_proj(const float* __restrict__ mol,
                                              const float* __restrict__ W,
                                              float* __restrict__ part) {
  __shared__ float molS[40 * 64];
  int tid = threadIdx.x;
  int d0 = blockIdx.x * 40;
  for (int i = tid; i < 40 * 64; i += 256)
    molS[i] = mol[(size_t)(i & 63) * 10000 + d0 + (i >> 6)];
  __syncthreads();
  int p0 = (tid & 63) * 4;
  int bh = (tid >> 6) * 16;
  float acc[4][16] = {};
  const float* w0 = W + (size_t)(p0 + 0) * 10000 + d0;
  const float* w1 = W + (size_t)(p0 + 1) * 10000 + d0;
  const float* w2 = W + (size_t)(p0 + 2) * 10000 + d0;
  const float* w3 = W + (size_t)(p0 + 3) * 10000 + d0;
#pragma unroll 4
  for (int dl = 0; dl < 40; ++dl) {
    const float wv[4] = {w0[dl], w1[dl], w2[dl], w3[dl]};
    const float4* m4 = (const float4*)(molS + dl * 64 + bh);
#pragma unroll
    for (int q = 0; q < 4; ++q) {
      float4 mv = m4[q];
#pragma unroll
      for (int pp = 0; pp < 4; ++pp) {
        acc[pp][4 * q + 0] += wv[pp] * mv.x;
        acc[pp][4 * q + 1] += wv[pp] * mv.y;
        acc[pp][4 * q + 2] += wv[pp] * mv.z;
        acc[pp][4 * q + 3] += wv[pp] * mv.w;
      }
    }
  }
#pragma unroll
  for (int b = 0; b < 16; ++b) {
    float4 v = make_float4(acc[0][b], acc[1][b], acc[2][b], acc[3][b]);
    *(float4*)(part + (size_t)blockIdx.x * 16384 + (bh + b) * 256 + p0) = v;
  }
}

// ---------------- reduce partials + bias ----------------
__global__ void k_red(const float* __restrict__ part, const float* __restrict__ bias,
                      float* __restrict__ out) {
  int tid = threadIdx.x;
  int b = blockIdx.x;
  float acc = bias[tid];
#pragma unroll 8
  for (int ch = 0; ch < 250; ++ch)
    acc += part[(size_t)ch * 16384 + b * 256 + tid];
  out[b * 256 + tid] = acc;
}

extern "C" void kernel_launch(void* const* d_in, const int* in_sizes, int n_in,
                              void* d_out, int out_size, void* d_ws, size_t ws_size,
                              hipStream_t stream) {
  const float* atom  = (const float*)d_in[0];   // [10,10000]
  const float* pos   = (const float*)d_in[1];   // [128,10000]
  const float* clo   = (const float*)d_in[2];   // [10000]
  const float* W     = (const float*)d_in[3];   // [256,10000]
  const float* bias  = (const float*)d_in[4];   // [256]
  const float* tmask = (const float*)d_in[5];   // [64,128]
  const float* rmask = (const float*)d_in[6];   // [64,8]
  const int*   aidx  = (const int*)d_in[7];     // [64,128]
  const int*   rpos  = (const int*)d_in[8];     // [64,8,2]
  float* out = (float*)d_out;                   // [64,256]

  char* ws = (char*)d_ws;
  size_t off = 0;
  auto alloc = [&](size_t n) { off = (off + 255) & ~(size_t)255; size_t o = off; off += n; return o; };
  char* regA   = ws + alloc(16777216);          // Bi (2.66MB) / partials (16.4MB)
  float2* Bi   = (float2*)regA;                 // Bi used by i1/i2 before proj writes part
  float*  part = (float*)regA;
  float2* spec = (float2*)(ws + alloc((size_t)NSIG * FS * 8));
  float2* G    = (float2*)(ws + alloc((size_t)64 * 10000 * 8));
  float*  mol  = (float*)(ws + alloc((size_t)64 * 10000 * 4));

  k_fwd<<<dim3(NSIG, 4), dim3(256), 0, stream>>>(atom, pos, clo, spec);
  k_mix<<<dim3(20, 32), dim3(256), 0, stream>>>(spec, tmask, rmask, aidx, rpos, G);
  k_i1<<<dim3(64, 6), dim3(256), 0, stream>>>(G, Bi);
  k_i2<<<dim3(64, 10), dim3(256), 0, stream>>>(Bi, mol);
  k_proj<<<dim3(250), dim3(256), 0, stream>>>(mol, W, part);
  k_red<<<dim3(64), dim3(256), 0, stream>>>(part, bias, out);
}

// Round 13
// 193.890 us; speedup vs baseline: 1.2312x; 1.0286x over previous
//
#include <hip/hip_runtime.h>

#define PI2 6.28318530717958647692f

// D = 10000 = 100 x 100; F = 5001; signals: 128 pos + 10 atom + 1 closure = 139
#define NSIG 139
#define FS   5120      // spectrum row stride (float2)

// ---------------- fused forward (f1+f2), Hermitian-paired, LDS-resident ----------------
// Block = (sig, sixth q). k1 range: q*10 .. min(q*10+9, 50).
// Phase 1: stage x (40 KB LDS); ONE tile per thread (1 k1 x 4 n2), DFT100 over n1
//          with twiddle recurrence; Hermitian pairing gives rows k1 and (100-k1)%100.
// Phase 2: write the 2*nk1 B-rows into LDS (overlays xs; 20*200 floats = 16 KB).
// Phase 3: f2 column-DFT from LDS rows, k2 in [0,52), ~2 tiles/thread, write spec.
// All trig inline (__sincosf); products (n2+j)*k1 <= 99*99 < 10000 -> small exact angles.
__global__ __launch_bounds__(256) void k_fwd(
                     const float* __restrict__ atom, const float* __restrict__ pos,
                     const float* __restrict__ clo, float2* __restrict__ spec) {
  __shared__ float xs[10000];   // phase1: x signal; phase3: B rows (row stride 200 floats)
  unsigned sig = blockIdx.x, q = blockIdx.y;
  unsigned k1base = q * 10u;
  unsigned nk1 = (k1base + 10u <= 51u) ? 10u : (51u - k1base);   // q=5 -> 1 (k1=50)
  const float* xb = (sig < 128u) ? (pos + sig * 10000u)
                   : ((sig < 138u) ? (atom + (sig - 128u) * 10000u) : clo);
  int tid = threadIdx.x;
  for (int i = tid; i < 2500; i += 256)
    *(float4*)(xs + 4 * i) = *(const float4*)(xb + 4 * i);
  __syncthreads();

  // ---- phase 1: one tile per thread, results held in registers ----
  float resA[8], resB[8];
  unsigned ntile1 = nk1 * 25u;
  unsigned k1l = tid / 25u, n2 = (tid % 25u) * 4u;
  bool have = (unsigned)tid < ntile1;
  if (have) {
    unsigned k1 = k1base + k1l;
    float cth, sth;
    __sincosf(PI2 * (float)k1 * 0.01f, &sth, &cth);
    float c = 1.0f, s = 0.0f;
    float ar[4] = {}, as[4] = {};
#pragma unroll 4
    for (int n1 = 0; n1 < 100; ++n1) {
      const float4 xv = *(const float4*)(xs + n1 * 100 + n2);
      ar[0] += xv.x * c; as[0] += xv.x * s;
      ar[1] += xv.y * c; as[1] += xv.y * s;
      ar[2] += xv.z * c; as[2] += xv.z * s;
      ar[3] += xv.w * c; as[3] += xv.w * s;
      float cn = c * cth - s * sth;
      float sn = s * cth + c * sth;
      c = cn; s = sn;
    }
    unsigned rb = (100u - k1) % 100u;
#pragma unroll
    for (int j = 0; j < 4; ++j) {
      float swA, cwA, swB, cwB;
      __sincosf(PI2 * (float)((n2 + j) * k1) * 1e-4f, &swA, &cwA);
      __sincosf(PI2 * (float)((n2 + j) * rb) * 1e-4f, &swB, &cwB);
      resA[2 * j + 0] = ar[j] * cwA - as[j] * swA;
      resA[2 * j + 1] = -(as[j] * cwA + ar[j] * swA);
      resB[2 * j + 0] = ar[j] * cwB + as[j] * swB;
      resB[2 * j + 1] = as[j] * cwB - ar[j] * swB;
    }
  }
  __syncthreads();   // all xs reads complete

  // ---- phase 2: write B rows into LDS (overlay xs). local row rA=k1l, rB=nk1+k1l ----
  if (have) {
    float* pA = xs + k1l * 200u + n2 * 2u;
    float* pB = xs + (nk1 + k1l) * 200u + n2 * 2u;
    *(float4*)(pA + 0) = make_float4(resA[0], resA[1], resA[2], resA[3]);
    *(float4*)(pA + 4) = make_float4(resA[4], resA[5], resA[6], resA[7]);
    *(float4*)(pB + 0) = make_float4(resB[0], resB[1], resB[2], resB[3]);
    *(float4*)(pB + 4) = make_float4(resB[4], resB[5], resB[6], resB[7]);
  }
  __syncthreads();

  // ---- phase 3: f2 from LDS. tiles: (2*nk1 rows) x 26 k2-pairs ----
  unsigned nrow = 2u * nk1;
  unsigned ntile3 = nrow * 26u;
  for (unsigned t = tid; t < ntile3; t += 256u) {
    unsigned lr = t / 26u, k2 = (t % 26u) * 2u;
    unsigned gk1 = (lr < nk1) ? (k1base + lr) : ((100u - (k1base + (lr - nk1))) % 100u);
    const float* brow = xs + lr * 200u;
    float cthA, sthA, cthB, sthB;
    __sincosf(PI2 * (float)k2 * 0.01f, &sthA, &cthA);
    __sincosf(PI2 * (float)(k2 + 1) * 0.01f, &sthB, &cthB);
    float cA = 1.0f, sA = 0.0f, cB = 1.0f, sB = 0.0f;
    float reA = 0.f, imA = 0.f, reB = 0.f, imB = 0.f;
#pragma unroll 4
    for (int n2i = 0; n2i < 100; n2i += 2) {
      const float4 b0 = *(const float4*)(brow + 2 * n2i);   // 2 complex (LDS, same addr across k2 lanes -> broadcast)
      reA += b0.x * cA + b0.y * sA;  imA += b0.y * cA - b0.x * sA;
      reB += b0.x * cB + b0.y * sB;  imB += b0.y * cB - b0.x * sB;
      float cA1 = cA * cthA - sA * sthA, sA1 = sA * cthA + cA * sthA;
      float cB1 = cB * cthB - sB * sthB, sB1 = sB * cthB + cB * sthB;
      reA += b0.z * cA1 + b0.w * sA1;  imA += b0.w * cA1 - b0.z * sA1;
      reB += b0.z * cB1 + b0.w * sB1;  imB += b0.w * cB1 - b0.z * sB1;
      cA = cA1 * cthA - sA1 * sthA; sA = sA1 * cthA + cA1 * sthA;
      cB = cB1 * cthB - sB1 * sthB; sB = sB1 * cthB + cB1 * sthB;
    }
    unsigned kA = gk1 + 100u * k2;
    unsigned kB = gk1 + 100u * (k2 + 1);
    if (kA <= 5000u) spec[sig * FS + kA] = make_float2(reA, imA);
    if (kB <= 5000u) spec[sig * FS + kB] = make_float2(reB, imB);
  }
}

// ---------------- mix: b-tile 2, 640 blocks, serial Fp loads (round-10 proven shape) ----------------
__global__ void k_mix(const float2* __restrict__ spec,
                      const float* __restrict__ tmask, const float* __restrict__ rmask,
                      const int* __restrict__ aidx, const int* __restrict__ rpos,
                      float2* __restrict__ G) {
  __shared__ float2 FaS[10][256];
  __shared__ float2 FcS[256];
  __shared__ float tmS[2][128];
  __shared__ int   aiS[2][128];
  __shared__ float rmS[2][8];
  __shared__ int   rpS[2][8][2];
  int tid = threadIdx.x;
  int k = blockIdx.x * 256 + tid;
  int kc = k > 5000 ? 5000 : k;
  int b0 = blockIdx.y * 2;
#pragma unroll
  for (int a = 0; a < 10; ++a) FaS[a][tid] = spec[(128 + a) * FS + kc];
  FcS[tid] = spec[138 * FS + kc];
  for (int i = tid; i < 2 * 128; i += 256) {
    int bb = i >> 7, ss = i & 127;
    tmS[bb][ss] = tmask[(b0 + bb) * 128 + ss];
    aiS[bb][ss] = aidx[(b0 + bb) * 128 + ss];
  }
  if (tid < 16) {
    int bb = tid >> 3, rr = tid & 7;
    rmS[bb][rr] = rmask[(b0 + bb) * 8 + rr];
    rpS[bb][rr][0] = rpos[((b0 + bb) * 8 + rr) * 2 + 0];
    rpS[bb][rr][1] = rpos[((b0 + bb) * 8 + rr) * 2 + 1];
  }
  __syncthreads();
  float fr[2] = {}, fi[2] = {};
#pragma unroll 8
  for (int s = 0; s < 128; ++s) {
    float2 fp = spec[s * FS + kc];   // address-independent across s -> ILP
#pragma unroll
    for (int b = 0; b < 2; ++b) {
      int a = aiS[b][s];
      float tm = tmS[b][s];
      float2 fa = FaS[a][tid];
      float tr = fa.x * fp.x - fa.y * fp.y;
      float ti = fa.x * fp.y + fa.y * fp.x;
      fr[b] += tm * tr;
      fi[b] += tm * ti;
    }
  }
  float2 fc = FcS[tid];
#pragma unroll
  for (int r = 0; r < 8; ++r) {
#pragma unroll
    for (int b = 0; b < 2; ++b) {
      int p0 = rpS[b][r][0], p1 = rpS[b][r][1];
      float rm = rmS[b][r];
      float2 f0 = spec[p0 * FS + kc];
      float2 f1 = spec[p1 * FS + kc];
      float tr = f0.x * f1.x - f0.y * f1.y;
      float ti = f0.x * f1.y + f0.y * f1.x;
      float ur = tr * fc.x - ti * fc.y;
      float ui = tr * fc.y + ti * fc.x;
      fr[b] += rm * ur;
      fi[b] += rm * ui;
    }
  }
  if (k <= 5000) {
#pragma unroll
    for (int b = 0; b < 2; ++b) {
      float fib = (k == 0 || k == 5000) ? 0.0f : fi[b];  // exact Hermitian guard
      G[(size_t)(b0 + b) * 10000 + k] = make_float2(fr[b], fib);
      if (k >= 1 && k <= 4999)
        G[(size_t)(b0 + b) * 10000 + (10000 - k)] = make_float2(fr[b], -fib);
    }
  }
}

// ---------------- inverse stage 1 (Hermitian-halved, LDS-staged, twiddle recurrence, inline trig) ----------------
__global__ void k_i1(const float2* __restrict__ G, float2* __restrict__ Bi) {
  __shared__ float gs[10400];   // 100 rows x 52 complex (104 floats/row)
  unsigned sig = blockIdx.x;
  const float* gp = (const float*)(G + sig * 10000u);
  for (int i = threadIdx.x; i < 2600; i += 256) {
    int row = i / 26, c4 = i % 26;
    *(float4*)(gs + row * 104 + c4 * 4) = *(const float4*)(gp + row * 200 + c4 * 4);
  }
  __syncthreads();
  unsigned tt = blockIdx.y * 256u + threadIdx.x;
  if (tt >= 1300u) return;
  unsigned m1 = (tt / 26u) * 2u, n2 = (tt % 26u) * 2u;
  float cthA, sthA, cthB, sthB;
  __sincosf(PI2 * (float)m1 * 0.01f, &sthA, &cthA);
  __sincosf(PI2 * (float)(m1 + 1) * 0.01f, &sthB, &cthB);
  float cA = 1.0f, sA = 0.0f, cB = 1.0f, sB = 0.0f;
  float reA[2] = {}, imA[2] = {};   // col n2   for m1, m1+1
  float reB[2] = {}, imB[2] = {};   // col n2+1 for m1, m1+1
#pragma unroll 4
  for (int n1 = 0; n1 < 100; ++n1) {
    const float4 gv = *(const float4*)(gs + n1 * 104 + n2 * 2);  // 2 complex, LDS
    reA[0] += gv.x * cA - gv.y * sA;  imA[0] += gv.y * cA + gv.x * sA;
    reB[0] += gv.z * cA - gv.w * sA;  imB[0] += gv.w * cA + gv.z * sA;
    reA[1] += gv.x * cB - gv.y * sB;  imA[1] += gv.y * cB + gv.x * sB;
    reB[1] += gv.z * cB - gv.w * sB;  imB[1] += gv.w * cB + gv.z * sB;
    float cA1 = cA * cthA - sA * sthA, sA1 = sA * cthA + cA * sthA;
    float cB1 = cB * cthB - sB * sthB, sB1 = sB * cthB + cB * sthB;
    cA = cA1; sA = sA1; cB = cB1; sB = sB1;
  }
  float w0 = (n2 == 0 || n2 == 50) ? 0.5f : 1.0f;
  float w1 = (n2 == 50) ? 0.0f : 1.0f;
#pragma unroll
  for (int i = 0; i < 2; ++i) {
    float sw0, cw0, sw1, cw1;
    __sincosf(PI2 * (float)(n2 * (m1 + i)) * 1e-4f, &sw0, &cw0);
    __sincosf(PI2 * (float)((n2 + 1) * (m1 + i)) * 1e-4f, &sw1, &cw1);
    float4 outv;
    outv.x = (reA[i] * cw0 - imA[i] * sw0) * w0;
    outv.y = (imA[i] * cw0 + reA[i] * sw0) * w0;
    outv.z = (reB[i] * cw1 - imB[i] * sw1) * w1;
    outv.w = (imB[i] * cw1 + reB[i] * sw1) * w1;
    *(float4*)((float*)Bi + (sig * 5200u + (m1 + i) * 52u + n2) * 2) = outv;
  }
}

// ---------------- inverse stage 2 (Hermitian-halved, LDS-staged, twiddle recurrence, inline trig) ----------------
__global__ void k_i2(const float2* __restrict__ Bi, float* __restrict__ mol) {
  __shared__ float bs[10400];   // 100 rows x 52 complex
  unsigned sig = blockIdx.x;
  const float* bp = (const float*)Bi + sig * 10400u;
  for (int i = threadIdx.x; i < 2600; i += 256)
    *(float4*)(bs + 4 * i) = *(const float4*)(bp + 4 * i);
  __syncthreads();
  unsigned tt = blockIdx.y * 256u + threadIdx.x;
  if (tt >= 2500u) return;
  unsigned m1 = (tt / 50u) * 2u;   // 50 groups -> m1 = 0..98
  unsigned m2 = (tt % 50u) * 2u;   // 50 groups, fastest
  const float* b0 = bs + m1 * 104u;
  const float* b1 = b0 + 104;
  float cthA, sthA, cthB, sthB;
  __sincosf(PI2 * (float)m2 * 0.01f, &sthA, &cthA);
  __sincosf(PI2 * (float)(m2 + 1) * 0.01f, &sthB, &cthB);
  float cA = 1.0f, sA = 0.0f, cB = 1.0f, sB = 0.0f;
  float re[2][2] = {};
#pragma unroll 4
  for (int jj = 0; jj < 26; ++jj) {
    int n2 = 2 * jj;
    const float4 v0 = *(const float4*)(b0 + 2 * n2);
    const float4 v1 = *(const float4*)(b1 + 2 * n2);
    re[0][0] += v0.x * cA - v0.y * sA;
    re[1][0] += v1.x * cA - v1.y * sA;
    re[0][1] += v0.x * cB - v0.y * sB;
    re[1][1] += v1.x * cB - v1.y * sB;
    float cA1 = cA * cthA - sA * sthA, sA1 = sA * cthA + cA * sthA;
    float cB1 = cB * cthB - sB * sthB, sB1 = sB * cthB + cB * sthB;
    re[0][0] += v0.z * cA1 - v0.w * sA1;
    re[1][0] += v1.z * cA1 - v1.w * sA1;
    re[0][1] += v0.z * cB1 - v0.w * sB1;
    re[1][1] += v1.z * cB1 - v1.w * sB1;
    cA = cA1 * cthA - sA1 * sthA; sA = sA1 * cthA + cA1 * sthA;
    cB = cB1 * cthB - sB1 * sthB; sB = sB1 * cthB + cB1 * sthB;
  }
#pragma unroll
  for (int i = 0; i < 2; ++i)
#pragma unroll
    for (int j = 0; j < 2; ++j)
      mol[sig * 10000u + (m1 + i) + 100u * (m2 + j)] = re[i][j] * 2e-4f;
}

// ---------------- projection: 250 chunks of 40 (round-6 proven) ----------------
__global__ __launch_bounds__(256) void k_proj(const float* __restrict__ mol,
                                              const float* __restrict__ W,
                                              float* __restrict__ part) {
  __shared__ float molS[40 * 64];
  int tid = threadIdx.x;
  int d0 = blockIdx.x * 40;
  for (int i = tid; i < 40 * 64; i += 256)
    molS[i] = mol[(size_t)(i & 63) * 10000 + d0 + (i >> 6)];
  __syncthreads();
  int p0 = (tid & 63) * 4;
  int bh = (tid >> 6) * 16;
  float acc[4][16] = {};
  const float* w0 = W + (size_t)(p0 + 0) * 10000 + d0;
  const float* w1 = W + (size_t)(p0 + 1) * 10000 + d0;
  const float* w2 = W + (size_t)(p0 + 2) * 10000 + d0;
  const float* w3 = W + (size_t)(p0 + 3) * 10000 + d0;
#pragma unroll 4
  for (int dl = 0; dl < 40; ++dl) {
    const float wv[4] = {w0[dl], w1[dl], w2[dl], w3[dl]};
    const float4* m4 = (const float4*)(molS + dl * 64 + bh);
#pragma unroll
    for (int q = 0; q < 4; ++q) {
      float4 mv = m4[q];
#pragma unroll
      for (int pp = 0; pp < 4; ++pp) {
        acc[pp][4 * q + 0] += wv[pp] * mv.x;
        acc[pp][4 * q + 1] += wv[pp] * mv.y;
        acc[pp][4 * q + 2] += wv[pp] * mv.z;
        acc[pp][4 * q + 3] += wv[pp] * mv.w;
      }
    }
  }
#pragma unroll
  for (int b = 0; b < 16; ++b) {
    float4 v = make_float4(acc[0][b], acc[1][b], acc[2][b], acc[3][b]);
    *(float4*)(part + (size_t)blockIdx.x * 16384 + (bh + b) * 256 + p0) = v;
  }
}

// ---------------- reduce partials + bias ----------------
__global__ void k_red(const float* __restrict__ part, const float* __restrict__ bias,
                      float* __restrict__ out) {
  int tid = threadIdx.x;
  int b = blockIdx.x;
  float acc = bias[tid];
#pragma unroll 8
  for (int ch = 0; ch < 250; ++ch)
    acc += part[(size_t)ch * 16384 + b * 256 + tid];
  out[b * 256 + tid] = acc;
}

extern "C" void kernel_launch(void* const* d_in, const int* in_sizes, int n_in,
                              void* d_out, int out_size, void* d_ws, size_t ws_size,
                              hipStream_t stream) {
  const float* atom  = (const float*)d_in[0];   // [10,10000]
  const float* pos   = (const float*)d_in[1];   // [128,10000]
  const float* clo   = (const float*)d_in[2];   // [10000]
  const float* W     = (const float*)d_in[3];   // [256,10000]
  const float* bias  = (const float*)d_in[4];   // [256]
  const float* tmask = (const float*)d_in[5];   // [64,128]
  const float* rmask = (const float*)d_in[6];   // [64,8]
  const int*   aidx  = (const int*)d_in[7];     // [64,128]
  const int*   rpos  = (const int*)d_in[8];     // [64,8,2]
  float* out = (float*)d_out;                   // [64,256]

  char* ws = (char*)d_ws;
  size_t off = 0;
  auto alloc = [&](size_t n) { off = (off + 255) & ~(size_t)255; size_t o = off; off += n; return o; };
  char* regA   = ws + alloc(16777216);          // Bi (2.66MB) / partials (16.4MB)
  float2* Bi   = (float2*)regA;                 // Bi used by i1/i2 before proj writes part
  float*  part = (float*)regA;
  float2* spec = (float2*)(ws + alloc((size_t)NSIG * FS * 8));
  float2* G    = (float2*)(ws + alloc((size_t)64 * 10000 * 8));
  float*  mol  = (float*)(ws + alloc((size_t)64 * 10000 * 4));

  k_fwd<<<dim3(NSIG, 6), dim3(256), 0, stream>>>(atom, pos, clo, spec);
  k_mix<<<dim3(20, 32), dim3(256), 0, stream>>>(spec, tmask, rmask, aidx, rpos, G);
  k_i1<<<dim3(64, 6), dim3(256), 0, stream>>>(G, Bi);
  k_i2<<<dim3(64, 10), dim3(256), 0, stream>>>(Bi, mol);
  k_proj<<<dim3(250), dim3(256), 0, stream>>>(mol, W, part);
  k_red<<<dim3(64), dim3(256), 0, stream>>>(part, bias, out);
}